// Round 4
// baseline (466.578 us; speedup 1.0000x reference)
//
#include <hip/hip_runtime.h>
#include <hip/hip_bf16.h>
#include <math.h>

#define D_IN  128
#define D_OUT 64
#define NGRP  8      // row-range groups, matched to 8 XCDs via blockIdx&7
#define SHIFT 14     // local-row bits in packed pair (span <= 16384)

// ---------------------------------------------------------------------------
// Edge-index dtype detection: reference declares int64, harness may pass int32.
// If buffer is little-endian int64 with values < 2^31, every odd u32 is 0.
// ---------------------------------------------------------------------------
__global__ void k_detect(const unsigned int* __restrict__ u, int* __restrict__ flag) {
    __shared__ int nonzero;
    if (threadIdx.x == 0) nonzero = 0;
    __syncthreads();
    if (u[2 * threadIdx.x + 1] != 0u) atomicOr(&nonzero, 1);
    __syncthreads();
    if (threadIdx.x == 0) *flag = (nonzero == 0) ? 1 : 0;  // 1 => int64
}

__device__ __forceinline__ int edge_val(const void* ei, int is64, long long idx) {
    return is64 ? (int)((const long long*)ei)[idx] : ((const int*)ei)[idx];
}

// ---------------------------------------------------------------------------
// Multisplit: one sweep of the edge list; partition edges by row-range group
// g = r / span into 8 packed arrays: pair = (col << SHIFT) | (r - g*span).
// Per 2048-edge tile: LDS-rank within block (1 LDS atomic/edge), reserve a
// contiguous batch per group via 8 global atomics, write dense ~KB batches.
// ---------------------------------------------------------------------------
__global__ __launch_bounds__(256) void k_split(const void* __restrict__ ei,
        const int* __restrict__ flag, int* __restrict__ gcur,
        unsigned int* __restrict__ parts, long long E, int span, int cap) {
    __shared__ int scnt[NGRP];
    __shared__ int sbase[NGRP];
    const int is64 = *flag;
    const int tid  = threadIdx.x;
    const long long tile = 2048;

    for (long long t0 = (long long)blockIdx.x * tile; t0 < E;
         t0 += (long long)gridDim.x * tile) {
        if (tid < NGRP) scnt[tid] = 0;
        __syncthreads();
        int g8[8], c8[8], rl8[8], rk8[8];
#pragma unroll
        for (int j = 0; j < 8; ++j) {
            long long e = t0 + (long long)j * 256 + tid;
            if (e < E) {
                int r = edge_val(ei, is64, e);
                int c = edge_val(ei, is64, E + e);
                int g = r / span;
                g8[j] = g; rl8[j] = r - g * span; c8[j] = c;
                rk8[j] = atomicAdd(&scnt[g], 1);
            } else g8[j] = -1;
        }
        __syncthreads();
        if (tid < NGRP && scnt[tid] > 0)
            sbase[tid] = atomicAdd(&gcur[tid * 16], scnt[tid]);
        __syncthreads();
#pragma unroll
        for (int j = 0; j < 8; ++j) {
            if (g8[j] >= 0) {
                int pos = sbase[g8[j]] + rk8[j];
                parts[(size_t)g8[j] * cap + pos] =
                    ((unsigned int)c8[j] << SHIFT) | (unsigned int)rl8[j];
            }
        }
        __syncthreads();
    }
}

// ---------------------------------------------------------------------------
// Per-row degree count from packed partitions: group g's cnt slice (50 KB)
// and its 1.6 MB partition stream both fit the XCD's L2.
// ---------------------------------------------------------------------------
__global__ __launch_bounds__(256) void k_countp(const unsigned int* __restrict__ parts,
        const int* __restrict__ gcur, int* __restrict__ cnt, int span, int cap) {
    const int g  = blockIdx.x & (NGRP - 1);
    const int sz = gcur[g * 16];
    const unsigned int* p = parts + (size_t)g * cap;
    const int lo = g * span;
    const unsigned int mask = (1u << SHIFT) - 1u;
    const long long stride = (long long)(gridDim.x >> 3) * blockDim.x;
    for (long long i = (long long)(blockIdx.x >> 3) * blockDim.x + threadIdx.x;
         i < sz; i += stride)
        atomicAdd(&cnt[lo + (int)(p[i] & mask)], 1);
}

// dk[i] = dinv[i]^k, deg = cnt+1 (self loop). k read on-device.
__global__ void k_dk(const int* __restrict__ cnt, const int* __restrict__ kptr,
                     float* __restrict__ dk, int n) {
    int i = blockIdx.x * blockDim.x + threadIdx.x;
    if (i >= n) return;
    int kk = kptr[0];
    if (kk < 0 || kk > 1000) {
        float kf = ((const float*)kptr)[0];
        kk = (kf > 0.f && kf < 1000.f) ? (int)(kf + 0.5f) : 2;
    }
    float deg = (float)(cnt[i] + 1);
    float dinv = 1.0f / sqrtf(deg);
    float v = 1.0f;
    for (int t = 0; t < kk; ++t) v *= dinv;
    dk[i] = v;
}

// ---------------------------------------------------------------------------
// Exclusive scan of cnt -> rowptr (+cursor copy). CHUNK=1024, 3 kernels.
// ---------------------------------------------------------------------------
__global__ __launch_bounds__(256) void k_chunk_sum(const int* __restrict__ cnt,
                                                   int* __restrict__ csum, int n) {
    __shared__ int sm[256];
    int tid = threadIdx.x;
    int base = blockIdx.x * 1024 + tid * 4;
    int s = 0;
#pragma unroll
    for (int j = 0; j < 4; ++j) { int idx = base + j; if (idx < n) s += cnt[idx]; }
    sm[tid] = s; __syncthreads();
    for (int o = 128; o > 0; o >>= 1) { if (tid < o) sm[tid] += sm[tid + o]; __syncthreads(); }
    if (tid == 0) csum[blockIdx.x] = sm[0];
}

// single block; requires nchunks <= 128 (n=100000 -> 98)
__global__ void k_scan_chunks(const int* __restrict__ cs, int* __restrict__ co,
                              int* __restrict__ rowptr, int nchunks, int n) {
    __shared__ int sm[128];
    int tid = threadIdx.x;
    int v = (tid < nchunks) ? cs[tid] : 0;
    sm[tid] = v; __syncthreads();
    for (int o = 1; o < 128; o <<= 1) {
        int a = (tid >= o) ? sm[tid - o] : 0;
        __syncthreads();
        sm[tid] += a;
        __syncthreads();
    }
    if (tid < nchunks) co[tid] = sm[tid] - v;
    if (tid == 127) rowptr[n] = sm[127];
}

__global__ __launch_bounds__(256) void k_scan_final(const int* __restrict__ cnt,
        const int* __restrict__ coff, int* __restrict__ rowptr,
        int* __restrict__ cursor, int n) {
    __shared__ int sm[256];
    int tid = threadIdx.x;
    int base = blockIdx.x * 1024 + tid * 4;
    int v[4]; int t = 0;
#pragma unroll
    for (int j = 0; j < 4; ++j) { int idx = base + j; v[j] = (idx < n) ? cnt[idx] : 0; t += v[j]; }
    sm[tid] = t; __syncthreads();
    for (int o = 1; o < 256; o <<= 1) {
        int a = (tid >= o) ? sm[tid - o] : 0;
        __syncthreads();
        sm[tid] += a;
        __syncthreads();
    }
    int run = coff[blockIdx.x] + sm[tid] - t;
#pragma unroll
    for (int j = 0; j < 4; ++j) {
        int idx = base + j;
        if (idx < n) { rowptr[idx] = run; cursor[idx] = run; run += v[j]; }
    }
}

// ---------------------------------------------------------------------------
// y2[r][:] = dk[r] * (x[r] @ W^T). 64 rows/block, 4x4 micro-tile per thread.
// ---------------------------------------------------------------------------
__global__ __launch_bounds__(256) void k_gemm(const float* __restrict__ x,
        const float* __restrict__ W, const float* __restrict__ dk,
        float* __restrict__ y2, int n) {
    __shared__ float Wt[D_IN][D_OUT];   // 32 KB
    __shared__ float xsT[D_IN][64];     // 32 KB
    const int tid = threadIdx.x;
    const int row0 = blockIdx.x * 64;

    {   // stage W transposed
        const int c = tid & 63;
        const int dblk = (tid >> 6) * 32;
        const float* wr = &W[c * D_IN + dblk];
#pragma unroll
        for (int j = 0; j < 32; j += 4) {
            float4 w4 = *(const float4*)(wr + j);
            Wt[dblk + j + 0][c] = w4.x;
            Wt[dblk + j + 1][c] = w4.y;
            Wt[dblk + j + 2][c] = w4.z;
            Wt[dblk + j + 3][c] = w4.w;
        }
    }
    {   // stage x rows transposed
        const int r = tid & 63;
        const int h = tid >> 6;
        const int grow = row0 + r;
        const float* xr = &x[(size_t)grow * D_IN + h * 32];
#pragma unroll
        for (int j = 0; j < 32; j += 4) {
            float4 v = (grow < n) ? *(const float4*)(xr + j)
                                  : make_float4(0.f, 0.f, 0.f, 0.f);
            xsT[h * 32 + j + 0][r] = v.x;
            xsT[h * 32 + j + 1][r] = v.y;
            xsT[h * 32 + j + 2][r] = v.z;
            xsT[h * 32 + j + 3][r] = v.w;
        }
    }
    __syncthreads();

    const int tx = tid & 15;
    const int ty = tid >> 4;
    float acc[4][4] = {};
#pragma unroll 8
    for (int d = 0; d < D_IN; ++d) {
        float4 wv = *(const float4*)&Wt[d][tx * 4];
        float4 xv = *(const float4*)&xsT[d][ty * 4];
        acc[0][0] += xv.x * wv.x; acc[0][1] += xv.x * wv.y; acc[0][2] += xv.x * wv.z; acc[0][3] += xv.x * wv.w;
        acc[1][0] += xv.y * wv.x; acc[1][1] += xv.y * wv.y; acc[1][2] += xv.y * wv.z; acc[1][3] += xv.y * wv.w;
        acc[2][0] += xv.z * wv.x; acc[2][1] += xv.z * wv.y; acc[2][2] += xv.z * wv.z; acc[2][3] += xv.z * wv.w;
        acc[3][0] += xv.w * wv.x; acc[3][1] += xv.w * wv.y; acc[3][2] += xv.w * wv.z; acc[3][3] += xv.w * wv.w;
    }
#pragma unroll
    for (int i = 0; i < 4; ++i) {
        int rr = row0 + ty * 4 + i;
        if (rr < n) {
            float s = dk[rr];
            float4 o = make_float4(acc[i][0] * s, acc[i][1] * s, acc[i][2] * s, acc[i][3] * s);
            *(float4*)&y2[(size_t)rr * D_OUT + tx * 4] = o;
        }
    }
}

// ---------------------------------------------------------------------------
// CSR colidx build from packed partitions: stream 1.6 MB + write 1.6 MB
// colidx + 50 KB cursors, all resident in one XCD's L2.
// ---------------------------------------------------------------------------
__global__ __launch_bounds__(256) void k_scatterp(const unsigned int* __restrict__ parts,
        const int* __restrict__ gcur, int* __restrict__ cursor,
        int* __restrict__ colidx, int span, int cap) {
    const int g  = blockIdx.x & (NGRP - 1);
    const int sz = gcur[g * 16];
    const unsigned int* p = parts + (size_t)g * cap;
    const int lo = g * span;
    const unsigned int mask = (1u << SHIFT) - 1u;
    const long long stride = (long long)(gridDim.x >> 3) * blockDim.x;
    for (long long i = (long long)(blockIdx.x >> 3) * blockDim.x + threadIdx.x;
         i < sz; i += stride) {
        unsigned int q = p[i];
        int r = lo + (int)(q & mask);
        int c = (int)(q >> SHIFT);
        int pos = atomicAdd(&cursor[r], 1);
        colidx[pos] = c;
    }
}

// ---------------------------------------------------------------------------
// SpMM: one wave per row, lane = output feature (D_OUT == 64 == wave size).
// Rows XCD-grouped (blockIdx&7) so colidx reads hit the L2 that wrote them.
// out[i] = dk[i] * (y2[i] + sum_e y2[col_e]) + b
// ---------------------------------------------------------------------------
__global__ __launch_bounds__(256) void k_spmm(
        const int* __restrict__ rowptr, const int* __restrict__ colidx,
        const float* __restrict__ y2, const float* __restrict__ dk,
        const float* __restrict__ bias, float* __restrict__ out, int n, int span) {
    const int g   = blockIdx.x & (NGRP - 1);
    const int wv  = threadIdx.x >> 6;
    const int lane = threadIdx.x & 63;
    const int row = g * span + (blockIdx.x >> 3) * 4 + wv;
    const int hi  = min((g + 1) * span, n);
    if (row >= hi) return;

    int start = rowptr[row];
    int end   = rowptr[row + 1];
    float acc = y2[(size_t)row * D_OUT + lane];   // self loop term

    int e = start;
    for (; e + 8 <= end; e += 8) {
        int c0 = colidx[e + 0], c1 = colidx[e + 1], c2 = colidx[e + 2], c3 = colidx[e + 3];
        int c4 = colidx[e + 4], c5 = colidx[e + 5], c6 = colidx[e + 6], c7 = colidx[e + 7];
        float v0 = y2[(size_t)c0 * D_OUT + lane];
        float v1 = y2[(size_t)c1 * D_OUT + lane];
        float v2 = y2[(size_t)c2 * D_OUT + lane];
        float v3 = y2[(size_t)c3 * D_OUT + lane];
        float v4 = y2[(size_t)c4 * D_OUT + lane];
        float v5 = y2[(size_t)c5 * D_OUT + lane];
        float v6 = y2[(size_t)c6 * D_OUT + lane];
        float v7 = y2[(size_t)c7 * D_OUT + lane];
        acc += ((v0 + v1) + (v2 + v3)) + ((v4 + v5) + (v6 + v7));
    }
    for (; e < end; ++e)
        acc += y2[(size_t)colidx[e] * D_OUT + lane];

    out[(size_t)row * D_OUT + lane] = dk[row] * acc + bias[lane];
}

// ---------------------------------------------------------------------------
extern "C" void kernel_launch(void* const* d_in, const int* in_sizes, int n_in,
                              void* d_out, int out_size, void* d_ws, size_t ws_size,
                              hipStream_t stream) {
    const float* x    = (const float*)d_in[0];
    const void*  ei   = d_in[1];
    const float* W    = (const float*)d_in[2];
    const float* b    = (const float*)d_in[3];
    const int*   kptr = (const int*)d_in[4];

    const int       n = in_sizes[0] / D_IN;            // 100000
    const long long E = (long long)in_sizes[1] / 2;    // 3200000
    const int    span = (n + NGRP - 1) / NGRP;         // 12500 (<= 1<<SHIFT)
    const int     cap = (int)(E / NGRP) + 65536;       // statistical headroom

    char* ws = (char*)d_ws;
    size_t off = 0;
    auto alloc = [&](size_t bytes) -> void* {
        void* p = ws + off;
        off += (bytes + 255) & ~(size_t)255;
        return p;
    };
    int*          flag   = (int*)alloc(4);
    int*          gcur   = (int*)alloc(NGRP * 16 * 4);       // padded cursors
    int*          cnt    = (int*)alloc((size_t)n * 4);
    int*          rowptr = (int*)alloc(((size_t)n + 1) * 4);
    int*          cursor = (int*)alloc((size_t)n * 4);
    float*        dk     = (float*)alloc((size_t)n * 4);
    int*          csum   = (int*)alloc(128 * 4);
    int*          coff   = (int*)alloc(128 * 4);
    float*        y2     = (float*)alloc((size_t)n * D_OUT * 4);
    unsigned int* parts  = (unsigned int*)alloc((size_t)NGRP * cap * 4);
    int*          colidx = (int*)alloc((size_t)E * 4);
    (void)ws_size; (void)n_in; (void)out_size;

    const int nchunks = (n + 1023) / 1024;             // 98 (<=128 required)

    hipMemsetAsync(gcur, 0, NGRP * 16 * 4, stream);
    hipMemsetAsync(cnt, 0, (size_t)n * 4, stream);
    k_detect<<<1, 256, 0, stream>>>((const unsigned int*)ei, flag);
    k_split<<<1024, 256, 0, stream>>>(ei, flag, gcur, parts, E, span, cap);
    k_countp<<<1024, 256, 0, stream>>>(parts, gcur, cnt, span, cap);
    k_dk<<<(n + 255) / 256, 256, 0, stream>>>(cnt, kptr, dk, n);
    k_chunk_sum<<<nchunks, 256, 0, stream>>>(cnt, csum, n);
    k_scan_chunks<<<1, 128, 0, stream>>>(csum, coff, rowptr, nchunks, n);
    k_scan_final<<<nchunks, 256, 0, stream>>>(cnt, coff, rowptr, cursor, n);
    k_gemm<<<(n + 63) / 64, 256, 0, stream>>>(x, W, dk, y2, n);
    k_scatterp<<<1024, 256, 0, stream>>>(parts, gcur, cursor, colidx, span, cap);
    k_spmm<<<8 * ((span + 3) / 4), 256, 0, stream>>>(rowptr, colidx, y2, dk, b,
                                                     (float*)d_out, n, span);
}

// Round 5
// 238.499 us; speedup vs baseline: 1.9563x; 1.9563x over previous
//
#include <hip/hip_runtime.h>
#include <hip/hip_bf16.h>
#include <math.h>

#define D_IN   128
#define D_OUT  64
#define NGRP   8            // row-range groups, matched to 8 XCDs via blockIdx&7
#define SHIFT  14           // local-row bits in packed pair (span <= 16384)
#define PMASK  ((1u << SHIFT) - 1u)
#define SBROWS 192          // rows per sub-bucket
#define CAP2   8192         // max edges per sub-bucket (mean 6144, sigma 78 -> 26 sigma)
#define NSB_MAX 128

// ---------------------------------------------------------------------------
// Edge-index dtype detection (int64 vs int32, little-endian high-word probe).
// ---------------------------------------------------------------------------
__global__ void k_detect(const unsigned int* __restrict__ u, int* __restrict__ flag) {
    __shared__ int nonzero;
    if (threadIdx.x == 0) nonzero = 0;
    __syncthreads();
    if (u[2 * threadIdx.x + 1] != 0u) atomicOr(&nonzero, 1);
    __syncthreads();
    if (threadIdx.x == 0) *flag = (nonzero == 0) ? 1 : 0;  // 1 => int64
}

__device__ __forceinline__ int edge_val(const void* ei, int is64, long long idx) {
    return is64 ? (int)((const long long*)ei)[idx] : ((const int*)ei)[idx];
}

// ---------------------------------------------------------------------------
// Pass 1 multisplit: edges -> 8 row-range groups, pair = (col<<SHIFT)|(r-g*span).
// LDS-rank per 4096-edge tile, dense batch writes (global atomic per group/tile).
// g = r/span via magic mul (exact: err*n << 2^40), plus boundary fix-up.
// ---------------------------------------------------------------------------
__global__ __launch_bounds__(256) void k_split(const void* __restrict__ ei,
        const int* __restrict__ flag, int* __restrict__ gcur,
        unsigned int* __restrict__ parts1, long long E, int span,
        unsigned long long inv, int cap1) {
    __shared__ int scnt[NGRP];
    __shared__ int sbase[NGRP];
    const int is64 = *flag;
    const int tid  = threadIdx.x;
    const long long tile = 4096;

    for (long long t0 = (long long)blockIdx.x * tile; t0 < E;
         t0 += (long long)gridDim.x * tile) {
        if (tid < NGRP) scnt[tid] = 0;
        __syncthreads();
        int g16[16], rk16[16];
        unsigned int q16[16];
#pragma unroll
        for (int j = 0; j < 16; ++j) {
            long long e = t0 + (long long)j * 256 + tid;
            if (e < E) {
                int r = edge_val(ei, is64, e);
                int c = edge_val(ei, is64, E + e);
                int g = (int)(((unsigned long long)(unsigned int)r * inv) >> 40);
                while (r >= (g + 1) * span) ++g;   // fix-up (never taken for exact magic)
                while (r < g * span) --g;
                g16[j] = g;
                q16[j] = ((unsigned int)c << SHIFT) | (unsigned int)(r - g * span);
                rk16[j] = atomicAdd(&scnt[g], 1);
            } else g16[j] = -1;
        }
        __syncthreads();
        if (tid < NGRP && scnt[tid] > 0)
            sbase[tid] = atomicAdd(&gcur[tid * 16], scnt[tid]);
        __syncthreads();
#pragma unroll
        for (int j = 0; j < 16; ++j) {
            if (g16[j] >= 0) {
                int pos = sbase[g16[j]] + rk16[j];
                if (pos < cap1)
                    parts1[(size_t)g16[j] * cap1 + pos] = q16[j];
            }
        }
        __syncthreads();
    }
}

// ---------------------------------------------------------------------------
// Pass 2 multisplit: group partition -> sub-buckets of SBROWS rows.
// Same LDS-rank batching; pair kept unchanged. XCD-local via blockIdx&7.
// ---------------------------------------------------------------------------
__global__ __launch_bounds__(256) void k_split2(const unsigned int* __restrict__ parts1,
        const int* __restrict__ gcur, int* __restrict__ gcur2,
        unsigned int* __restrict__ parts2, int cap1, int nsb) {
    __shared__ int scnt[NSB_MAX];
    __shared__ int sbase[NSB_MAX];
    const int g   = blockIdx.x & (NGRP - 1);
    const int sz  = min(gcur[g * 16], cap1);
    const unsigned int* p = parts1 + (size_t)g * cap1;
    const int tid = threadIdx.x;
    const int tile = 4096;

    for (int t0 = (blockIdx.x >> 3) * tile; t0 < sz; t0 += (gridDim.x >> 3) * tile) {
        if (tid < nsb) scnt[tid] = 0;
        __syncthreads();
        int s16[16], rk16[16];
        unsigned int q16[16];
#pragma unroll
        for (int j = 0; j < 16; ++j) {
            int i = t0 + j * 256 + tid;
            if (i < sz) {
                unsigned int q = p[i];
                int sb = (int)(q & PMASK) / SBROWS;   // const divisor -> compiler magic
                s16[j] = sb; q16[j] = q;
                rk16[j] = atomicAdd(&scnt[sb], 1);
            } else s16[j] = -1;
        }
        __syncthreads();
        if (tid < nsb && scnt[tid] > 0)
            sbase[tid] = atomicAdd(&gcur2[(g * nsb + tid) * 16], scnt[tid]);
        __syncthreads();
#pragma unroll
        for (int j = 0; j < 16; ++j) {
            if (s16[j] >= 0) {
                int pos = sbase[s16[j]] + rk16[j];
                if (pos < CAP2)
                    parts2[(size_t)(g * nsb + s16[j]) * CAP2 + pos] = q16[j];
            }
        }
        __syncthreads();
    }
}

// ---------------------------------------------------------------------------
// Scan sub-bucket sizes -> global CSR base per sub-bucket; rowptr[n] = total.
// Single block, 3 entries/thread (8*nsb <= 768).
// ---------------------------------------------------------------------------
__global__ void k_scan_sb(const int* __restrict__ gcur2, int* __restrict__ sbbase,
                          int* __restrict__ rowptr, int total_sb, int n) {
    __shared__ int sm[256];
    const int tid = threadIdx.x;
    int v[3]; int t = 0;
#pragma unroll
    for (int j = 0; j < 3; ++j) {
        int idx = tid * 3 + j;
        v[j] = (idx < total_sb) ? min(gcur2[idx * 16], CAP2) : 0;
        t += v[j];
    }
    sm[tid] = t; __syncthreads();
    for (int o = 1; o < 256; o <<= 1) {
        int a = (tid >= o) ? sm[tid - o] : 0;
        __syncthreads();
        sm[tid] += a;
        __syncthreads();
    }
    int run = sm[tid] - t;
#pragma unroll
    for (int j = 0; j < 3; ++j) {
        int idx = tid * 3 + j;
        if (idx < total_sb) { sbbase[idx] = run; run += v[j]; }
    }
    if (tid == 255) rowptr[n] = sm[255];
}

// ---------------------------------------------------------------------------
// CSR-ify one sub-bucket entirely in LDS: count -> scan -> scatter -> write
// colidx SEQUENTIALLY (plus rowptr & cnt for its rows). No scattered global
// stores -> no write amplification.
// ---------------------------------------------------------------------------
__global__ __launch_bounds__(256) void k_cidx(const unsigned int* __restrict__ parts2,
        const int* __restrict__ gcur2, const int* __restrict__ sbbase,
        int* __restrict__ rowptr, int* __restrict__ cnt,
        int* __restrict__ colidx, int span, int nsb, int n) {
    __shared__ int scnt[256];
    __shared__ int ssum[256];
    __shared__ int scur[256];
    __shared__ unsigned int clds[CAP2];    // 32 KB

    const int g   = blockIdx.x & (NGRP - 1);
    const int sb  = blockIdx.x >> 3;
    if (sb >= nsb) return;
    const int sbi = g * nsb + sb;
    const int sz  = min(gcur2[sbi * 16], CAP2);
    const unsigned int* p = parts2 + (size_t)sbi * CAP2;
    const int row0l = sb * SBROWS;                    // group-local first row
    const int row0g = g * span + row0l;               // global first row
    if (row0g >= n) return;
    const int rows_here = min(min(SBROWS, span - row0l), n - row0g);
    const int tid = threadIdx.x;
    const int sbb = sbbase[sbi];

    scnt[tid] = 0;
    __syncthreads();

    // Phase A: count rows (pairs kept in registers via static unroll)
    unsigned int q[32]; int rl[32];
#pragma unroll
    for (int j = 0; j < 32; ++j) {
        int i = j * 256 + tid;
        if (i < sz) {
            q[j]  = p[i];
            rl[j] = (int)(q[j] & PMASK) - row0l;
            atomicAdd(&scnt[rl[j]], 1);
        }
    }
    __syncthreads();

    // inclusive scan of counts
    ssum[tid] = scnt[tid];
    __syncthreads();
    for (int o = 1; o < 256; o <<= 1) {
        int a = (tid >= o) ? ssum[tid - o] : 0;
        __syncthreads();
        ssum[tid] += a;
        __syncthreads();
    }
    int excl = ssum[tid] - scnt[tid];
    scur[tid] = excl;
    if (tid < rows_here) {
        rowptr[row0g + tid] = sbb + excl;
        cnt[row0g + tid]    = scnt[tid];
    }
    __syncthreads();

    // Phase B: scatter cols into LDS in CSR order
#pragma unroll
    for (int j = 0; j < 32; ++j) {
        int i = j * 256 + tid;
        if (i < sz) {
            int pos = atomicAdd(&scur[rl[j]], 1);
            clds[pos] = q[j] >> SHIFT;
        }
    }
    __syncthreads();

    // sequential write-out
#pragma unroll
    for (int j = 0; j < 32; ++j) {
        int i = j * 256 + tid;
        if (i < sz) colidx[sbb + i] = (int)clds[i];
    }
}

// dk[i] = dinv[i]^k, deg = cnt+1 (self loop). k read on-device.
__global__ void k_dk(const int* __restrict__ cnt, const int* __restrict__ kptr,
                     float* __restrict__ dk, int n) {
    int i = blockIdx.x * blockDim.x + threadIdx.x;
    if (i >= n) return;
    int kk = kptr[0];
    if (kk < 0 || kk > 1000) {
        float kf = ((const float*)kptr)[0];
        kk = (kf > 0.f && kf < 1000.f) ? (int)(kf + 0.5f) : 2;
    }
    float deg = (float)(cnt[i] + 1);
    float dinv = 1.0f / sqrtf(deg);
    float v = 1.0f;
    for (int t = 0; t < kk; ++t) v *= dinv;
    dk[i] = v;
}

// ---------------------------------------------------------------------------
// y2[r][:] = dk[r] * (x[r] @ W^T). 64 rows/block, 4x4 micro-tile per thread.
// ---------------------------------------------------------------------------
__global__ __launch_bounds__(256) void k_gemm(const float* __restrict__ x,
        const float* __restrict__ W, const float* __restrict__ dk,
        float* __restrict__ y2, int n) {
    __shared__ float Wt[D_IN][D_OUT];   // 32 KB
    __shared__ float xsT[D_IN][64];     // 32 KB
    const int tid = threadIdx.x;
    const int row0 = blockIdx.x * 64;

    {
        const int c = tid & 63;
        const int dblk = (tid >> 6) * 32;
        const float* wr = &W[c * D_IN + dblk];
#pragma unroll
        for (int j = 0; j < 32; j += 4) {
            float4 w4 = *(const float4*)(wr + j);
            Wt[dblk + j + 0][c] = w4.x;
            Wt[dblk + j + 1][c] = w4.y;
            Wt[dblk + j + 2][c] = w4.z;
            Wt[dblk + j + 3][c] = w4.w;
        }
    }
    {
        const int r = tid & 63;
        const int h = tid >> 6;
        const int grow = row0 + r;
        const float* xr = &x[(size_t)grow * D_IN + h * 32];
#pragma unroll
        for (int j = 0; j < 32; j += 4) {
            float4 v = (grow < n) ? *(const float4*)(xr + j)
                                  : make_float4(0.f, 0.f, 0.f, 0.f);
            xsT[h * 32 + j + 0][r] = v.x;
            xsT[h * 32 + j + 1][r] = v.y;
            xsT[h * 32 + j + 2][r] = v.z;
            xsT[h * 32 + j + 3][r] = v.w;
        }
    }
    __syncthreads();

    const int tx = tid & 15;
    const int ty = tid >> 4;
    float acc[4][4] = {};
#pragma unroll 8
    for (int d = 0; d < D_IN; ++d) {
        float4 wv = *(const float4*)&Wt[d][tx * 4];
        float4 xv = *(const float4*)&xsT[d][ty * 4];
        acc[0][0] += xv.x * wv.x; acc[0][1] += xv.x * wv.y; acc[0][2] += xv.x * wv.z; acc[0][3] += xv.x * wv.w;
        acc[1][0] += xv.y * wv.x; acc[1][1] += xv.y * wv.y; acc[1][2] += xv.y * wv.z; acc[1][3] += xv.y * wv.w;
        acc[2][0] += xv.z * wv.x; acc[2][1] += xv.z * wv.y; acc[2][2] += xv.z * wv.z; acc[2][3] += xv.z * wv.w;
        acc[3][0] += xv.w * wv.x; acc[3][1] += xv.w * wv.y; acc[3][2] += xv.w * wv.z; acc[3][3] += xv.w * wv.w;
    }
#pragma unroll
    for (int i = 0; i < 4; ++i) {
        int rr = row0 + ty * 4 + i;
        if (rr < n) {
            float s = dk[rr];
            float4 o = make_float4(acc[i][0] * s, acc[i][1] * s, acc[i][2] * s, acc[i][3] * s);
            *(float4*)&y2[(size_t)rr * D_OUT + tx * 4] = o;
        }
    }
}

// ---------------------------------------------------------------------------
// SpMM: one wave per row, lane = output feature. Rows XCD-grouped.
// out[i] = dk[i] * (y2[i] + sum_e y2[col_e]) + b
// ---------------------------------------------------------------------------
__global__ __launch_bounds__(256) void k_spmm(
        const int* __restrict__ rowptr, const int* __restrict__ colidx,
        const float* __restrict__ y2, const float* __restrict__ dk,
        const float* __restrict__ bias, float* __restrict__ out, int n, int span) {
    const int g    = blockIdx.x & (NGRP - 1);
    const int wv   = threadIdx.x >> 6;
    const int lane = threadIdx.x & 63;
    const int row  = g * span + (blockIdx.x >> 3) * 4 + wv;
    const int hi   = min((g + 1) * span, n);
    if (row >= hi) return;

    int start = rowptr[row];
    int end   = rowptr[row + 1];
    float acc = y2[(size_t)row * D_OUT + lane];   // self loop term

    int e = start;
    for (; e + 8 <= end; e += 8) {
        int c0 = colidx[e + 0], c1 = colidx[e + 1], c2 = colidx[e + 2], c3 = colidx[e + 3];
        int c4 = colidx[e + 4], c5 = colidx[e + 5], c6 = colidx[e + 6], c7 = colidx[e + 7];
        float v0 = y2[(size_t)c0 * D_OUT + lane];
        float v1 = y2[(size_t)c1 * D_OUT + lane];
        float v2 = y2[(size_t)c2 * D_OUT + lane];
        float v3 = y2[(size_t)c3 * D_OUT + lane];
        float v4 = y2[(size_t)c4 * D_OUT + lane];
        float v5 = y2[(size_t)c5 * D_OUT + lane];
        float v6 = y2[(size_t)c6 * D_OUT + lane];
        float v7 = y2[(size_t)c7 * D_OUT + lane];
        acc += ((v0 + v1) + (v2 + v3)) + ((v4 + v5) + (v6 + v7));
    }
    for (; e < end; ++e)
        acc += y2[(size_t)colidx[e] * D_OUT + lane];

    out[(size_t)row * D_OUT + lane] = dk[row] * acc + bias[lane];
}

// ---------------------------------------------------------------------------
extern "C" void kernel_launch(void* const* d_in, const int* in_sizes, int n_in,
                              void* d_out, int out_size, void* d_ws, size_t ws_size,
                              hipStream_t stream) {
    const float* x    = (const float*)d_in[0];
    const void*  ei   = d_in[1];
    const float* W    = (const float*)d_in[2];
    const float* b    = (const float*)d_in[3];
    const int*   kptr = (const int*)d_in[4];

    const int       n = in_sizes[0] / D_IN;            // 100000
    const long long E = (long long)in_sizes[1] / 2;    // 3200000
    const int    span = (n + NGRP - 1) / NGRP;         // 12500 (<= 1<<SHIFT)
    const int     nsb = (span + SBROWS - 1) / SBROWS;  // 66 (<= NSB_MAX)
    const int    cap1 = (int)(E / NGRP) + 65536;
    const unsigned long long inv = ((1ULL << 40) + span - 1) / (unsigned long long)span;

    char* ws = (char*)d_ws;
    size_t off = 0;
    auto alloc = [&](size_t bytes) -> void* {
        void* p = ws + off;
        off += (bytes + 255) & ~(size_t)255;
        return p;
    };
    int*          flag   = (int*)alloc(4);
    int*          gcur   = (int*)alloc(NGRP * 16 * 4);
    int*          gcur2  = (int*)alloc((size_t)NGRP * nsb * 16 * 4);
    int*          sbbase = (int*)alloc((size_t)NGRP * nsb * 4);
    int*          cnt    = (int*)alloc((size_t)n * 4);
    int*          rowptr = (int*)alloc(((size_t)n + 1) * 4);
    float*        dk     = (float*)alloc((size_t)n * 4);
    // parts1 (8*cap1*4 = 14.9 MB); colidx aliases it (E*4 = 12.8 MB, parts1 dead after split2)
    size_t p1_bytes = (size_t)NGRP * cap1 * 4;
    size_t ci_bytes = (size_t)E * 4;
    unsigned int* parts1 = (unsigned int*)alloc(p1_bytes > ci_bytes ? p1_bytes : ci_bytes);
    int*          colidx = (int*)parts1;
    // parts2 (528*CAP2*4 = 17.3 MB); y2 aliases the same block (25.6 MB, parts2 dead after cidx)
    size_t p2_bytes = (size_t)NGRP * nsb * CAP2 * 4;
    size_t y2_bytes = (size_t)n * D_OUT * 4;
    unsigned int* parts2 = (unsigned int*)alloc(p2_bytes > y2_bytes ? p2_bytes : y2_bytes);
    float*        y2     = (float*)parts2;
    (void)ws_size; (void)n_in; (void)out_size;

    hipMemsetAsync(gcur, 0, NGRP * 16 * 4, stream);
    hipMemsetAsync(gcur2, 0, (size_t)NGRP * nsb * 16 * 4, stream);
    k_detect<<<1, 256, 0, stream>>>((const unsigned int*)ei, flag);
    k_split<<<1024, 256, 0, stream>>>(ei, flag, gcur, parts1, E, span, inv, cap1);
    k_split2<<<512, 256, 0, stream>>>(parts1, gcur, gcur2, parts2, cap1, nsb);
    k_scan_sb<<<1, 256, 0, stream>>>(gcur2, sbbase, rowptr, NGRP * nsb, n);
    k_cidx<<<NGRP * nsb, 256, 0, stream>>>(parts2, gcur2, sbbase, rowptr, cnt,
                                           colidx, span, nsb, n);
    k_dk<<<(n + 255) / 256, 256, 0, stream>>>(cnt, kptr, dk, n);
    k_gemm<<<(n + 63) / 64, 256, 0, stream>>>(x, W, dk, y2, n);
    k_spmm<<<NGRP * ((span + 3) / 4), 256, 0, stream>>>(rowptr, colidx, y2, dk, b,
                                                        (float*)d_out, n, span);
}

// Round 6
// 214.632 us; speedup vs baseline: 2.1738x; 1.1112x over previous
//
#include <hip/hip_runtime.h>
#include <hip/hip_bf16.h>
#include <math.h>

#define D_IN   128
#define D_OUT  64
#define NGRP   8            // row-range groups, matched to 8 XCDs via blockIdx&7
#define SHIFT  14           // local-row bits in packed pair (span <= 16384)
#define PMASK  ((1u << SHIFT) - 1u)
#define SBROWS 192          // rows per sub-bucket
#define CAP2   8192         // max edges per sub-bucket (mean ~6061, sigma ~78 -> 27 sigma)
#define NSB_MAX 128

__device__ __forceinline__ unsigned short f2bf(float f) {   // RTNE f32 -> bf16
    unsigned u = __float_as_uint(f);
    return (unsigned short)((u + 0x7FFFu + ((u >> 16) & 1u)) >> 16);
}
__device__ __forceinline__ float bf2f(unsigned short h) {
    return __uint_as_float(((unsigned)h) << 16);
}

// ---------------------------------------------------------------------------
// Edge-index dtype detection (int64 vs int32, little-endian high-word probe).
// ---------------------------------------------------------------------------
__global__ void k_detect(const unsigned int* __restrict__ u, int* __restrict__ flag) {
    __shared__ int nonzero;
    if (threadIdx.x == 0) nonzero = 0;
    __syncthreads();
    if (u[2 * threadIdx.x + 1] != 0u) atomicOr(&nonzero, 1);
    __syncthreads();
    if (threadIdx.x == 0) *flag = (nonzero == 0) ? 1 : 0;  // 1 => int64
}

__device__ __forceinline__ int edge_val(const void* ei, int is64, long long idx) {
    return is64 ? (int)((const long long*)ei)[idx] : ((const int*)ei)[idx];
}

// ---------------------------------------------------------------------------
// Pass 1 multisplit: edges -> 8 row-range groups, pair = (col<<SHIFT)|(r-g*span).
// LDS-rank per 4096-edge tile, dense batch writes (global atomic per group/tile).
// ---------------------------------------------------------------------------
__global__ __launch_bounds__(256) void k_split(const void* __restrict__ ei,
        const int* __restrict__ flag, int* __restrict__ gcur,
        unsigned int* __restrict__ parts1, long long E, int span,
        unsigned long long inv, int cap1) {
    __shared__ int scnt[NGRP];
    __shared__ int sbase[NGRP];
    const int is64 = *flag;
    const int tid  = threadIdx.x;
    const long long tile = 4096;

    for (long long t0 = (long long)blockIdx.x * tile; t0 < E;
         t0 += (long long)gridDim.x * tile) {
        if (tid < NGRP) scnt[tid] = 0;
        __syncthreads();
        int g16[16], rk16[16];
        unsigned int q16[16];
#pragma unroll
        for (int j = 0; j < 16; ++j) {
            long long e = t0 + (long long)j * 256 + tid;
            if (e < E) {
                int r = edge_val(ei, is64, e);
                int c = edge_val(ei, is64, E + e);
                int g = (int)(((unsigned long long)(unsigned int)r * inv) >> 40);
                while (r >= (g + 1) * span) ++g;
                while (r < g * span) --g;
                g16[j] = g;
                q16[j] = ((unsigned int)c << SHIFT) | (unsigned int)(r - g * span);
                rk16[j] = atomicAdd(&scnt[g], 1);
            } else g16[j] = -1;
        }
        __syncthreads();
        if (tid < NGRP && scnt[tid] > 0)
            sbase[tid] = atomicAdd(&gcur[tid * 16], scnt[tid]);
        __syncthreads();
#pragma unroll
        for (int j = 0; j < 16; ++j) {
            if (g16[j] >= 0) {
                int pos = sbase[g16[j]] + rk16[j];
                if (pos < cap1)
                    parts1[(size_t)g16[j] * cap1 + pos] = q16[j];
            }
        }
        __syncthreads();
    }
}

// ---------------------------------------------------------------------------
// Pass 2 multisplit: group partition -> sub-buckets of SBROWS rows.
// ---------------------------------------------------------------------------
__global__ __launch_bounds__(256) void k_split2(const unsigned int* __restrict__ parts1,
        const int* __restrict__ gcur, int* __restrict__ gcur2,
        unsigned int* __restrict__ parts2, int cap1, int nsb) {
    __shared__ int scnt[NSB_MAX];
    __shared__ int sbase[NSB_MAX];
    const int g   = blockIdx.x & (NGRP - 1);
    const int sz  = min(gcur[g * 16], cap1);
    const unsigned int* p = parts1 + (size_t)g * cap1;
    const int tid = threadIdx.x;
    const int tile = 4096;

    for (int t0 = (blockIdx.x >> 3) * tile; t0 < sz; t0 += (gridDim.x >> 3) * tile) {
        if (tid < nsb) scnt[tid] = 0;
        __syncthreads();
        int s16[16], rk16[16];
        unsigned int q16[16];
#pragma unroll
        for (int j = 0; j < 16; ++j) {
            int i = t0 + j * 256 + tid;
            if (i < sz) {
                unsigned int q = p[i];
                int sb = (int)(q & PMASK) / SBROWS;
                s16[j] = sb; q16[j] = q;
                rk16[j] = atomicAdd(&scnt[sb], 1);
            } else s16[j] = -1;
        }
        __syncthreads();
        if (tid < nsb && scnt[tid] > 0)
            sbase[tid] = atomicAdd(&gcur2[(g * nsb + tid) * 16], scnt[tid]);
        __syncthreads();
#pragma unroll
        for (int j = 0; j < 16; ++j) {
            if (s16[j] >= 0) {
                int pos = sbase[s16[j]] + rk16[j];
                if (pos < CAP2)
                    parts2[(size_t)(g * nsb + s16[j]) * CAP2 + pos] = q16[j];
            }
        }
        __syncthreads();
    }
}

// ---------------------------------------------------------------------------
// Scan sub-bucket sizes -> global CSR base per sub-bucket; rowptr[n] = total.
// ---------------------------------------------------------------------------
__global__ void k_scan_sb(const int* __restrict__ gcur2, int* __restrict__ sbbase,
                          int* __restrict__ rowptr, int total_sb, int n) {
    __shared__ int sm[256];
    const int tid = threadIdx.x;
    int v[3]; int t = 0;
#pragma unroll
    for (int j = 0; j < 3; ++j) {
        int idx = tid * 3 + j;
        v[j] = (idx < total_sb) ? min(gcur2[idx * 16], CAP2) : 0;
        t += v[j];
    }
    sm[tid] = t; __syncthreads();
    for (int o = 1; o < 256; o <<= 1) {
        int a = (tid >= o) ? sm[tid - o] : 0;
        __syncthreads();
        sm[tid] += a;
        __syncthreads();
    }
    int run = sm[tid] - t;
#pragma unroll
    for (int j = 0; j < 3; ++j) {
        int idx = tid * 3 + j;
        if (idx < total_sb) { sbbase[idx] = run; run += v[j]; }
    }
    if (tid == 255) rowptr[n] = sm[255];
}

// ---------------------------------------------------------------------------
// CSR-ify one sub-bucket entirely in LDS: count -> scan -> scatter -> write
// colidx SEQUENTIALLY. Also emits rowptr and (fused) dk = (deg+1)^(-k/2).
// ---------------------------------------------------------------------------
__global__ __launch_bounds__(256) void k_cidx(const unsigned int* __restrict__ parts2,
        const int* __restrict__ gcur2, const int* __restrict__ sbbase,
        int* __restrict__ rowptr, float* __restrict__ dk,
        const int* __restrict__ kptr, int* __restrict__ colidx,
        int span, int nsb, int n) {
    __shared__ int scnt[256];
    __shared__ int ssum[256];
    __shared__ int scur[256];
    __shared__ unsigned int clds[CAP2];    // 32 KB

    const int g   = blockIdx.x & (NGRP - 1);
    const int sb  = blockIdx.x >> 3;
    if (sb >= nsb) return;
    const int sbi = g * nsb + sb;
    const int sz  = min(gcur2[sbi * 16], CAP2);
    const unsigned int* p = parts2 + (size_t)sbi * CAP2;
    const int row0l = sb * SBROWS;
    const int row0g = g * span + row0l;
    if (row0g >= n) return;
    const int rows_here = min(min(SBROWS, span - row0l), n - row0g);
    const int tid = threadIdx.x;
    const int sbb = sbbase[sbi];

    scnt[tid] = 0;
    __syncthreads();

    unsigned int q[32]; int rl[32];
#pragma unroll
    for (int j = 0; j < 32; ++j) {
        int i = j * 256 + tid;
        if (i < sz) {
            q[j]  = p[i];
            rl[j] = (int)(q[j] & PMASK) - row0l;
            atomicAdd(&scnt[rl[j]], 1);
        }
    }
    __syncthreads();

    ssum[tid] = scnt[tid];
    __syncthreads();
    for (int o = 1; o < 256; o <<= 1) {
        int a = (tid >= o) ? ssum[tid - o] : 0;
        __syncthreads();
        ssum[tid] += a;
        __syncthreads();
    }
    int excl = ssum[tid] - scnt[tid];
    scur[tid] = excl;
    if (tid < rows_here) {
        rowptr[row0g + tid] = sbb + excl;
        // fused dk: deg = edge count + 1 (self loop)
        int kk = kptr[0];
        if (kk < 0 || kk > 1000) {
            float kf = ((const float*)kptr)[0];
            kk = (kf > 0.f && kf < 1000.f) ? (int)(kf + 0.5f) : 2;
        }
        float deg  = (float)(scnt[tid] + 1);
        float dinv = 1.0f / sqrtf(deg);
        float v = 1.0f;
        for (int t = 0; t < kk; ++t) v *= dinv;
        dk[row0g + tid] = v;
    }
    __syncthreads();

#pragma unroll
    for (int j = 0; j < 32; ++j) {
        int i = j * 256 + tid;
        if (i < sz) {
            int pos = atomicAdd(&scur[rl[j]], 1);
            clds[pos] = q[j] >> SHIFT;
        }
    }
    __syncthreads();

#pragma unroll
    for (int j = 0; j < 32; ++j) {
        int i = j * 256 + tid;
        if (i < sz) colidx[sbb + i] = (int)clds[i];
    }
}

// ---------------------------------------------------------------------------
// y2b[r][:] = bf16( dk[r] * (x[r] @ W^T) ). 64 rows/block, 4x4 micro-tile.
// ---------------------------------------------------------------------------
__global__ __launch_bounds__(256) void k_gemm(const float* __restrict__ x,
        const float* __restrict__ W, const float* __restrict__ dk,
        unsigned short* __restrict__ y2b, int n) {
    __shared__ float Wt[D_IN][D_OUT];   // 32 KB
    __shared__ float xsT[D_IN][64];     // 32 KB
    const int tid = threadIdx.x;
    const int row0 = blockIdx.x * 64;

    {
        const int c = tid & 63;
        const int dblk = (tid >> 6) * 32;
        const float* wr = &W[c * D_IN + dblk];
#pragma unroll
        for (int j = 0; j < 32; j += 4) {
            float4 w4 = *(const float4*)(wr + j);
            Wt[dblk + j + 0][c] = w4.x;
            Wt[dblk + j + 1][c] = w4.y;
            Wt[dblk + j + 2][c] = w4.z;
            Wt[dblk + j + 3][c] = w4.w;
        }
    }
    {
        const int r = tid & 63;
        const int h = tid >> 6;
        const int grow = row0 + r;
        const float* xr = &x[(size_t)grow * D_IN + h * 32];
#pragma unroll
        for (int j = 0; j < 32; j += 4) {
            float4 v = (grow < n) ? *(const float4*)(xr + j)
                                  : make_float4(0.f, 0.f, 0.f, 0.f);
            xsT[h * 32 + j + 0][r] = v.x;
            xsT[h * 32 + j + 1][r] = v.y;
            xsT[h * 32 + j + 2][r] = v.z;
            xsT[h * 32 + j + 3][r] = v.w;
        }
    }
    __syncthreads();

    const int tx = tid & 15;
    const int ty = tid >> 4;
    float acc[4][4] = {};
#pragma unroll 8
    for (int d = 0; d < D_IN; ++d) {
        float4 wv = *(const float4*)&Wt[d][tx * 4];
        float4 xv = *(const float4*)&xsT[d][ty * 4];
        acc[0][0] += xv.x * wv.x; acc[0][1] += xv.x * wv.y; acc[0][2] += xv.x * wv.z; acc[0][3] += xv.x * wv.w;
        acc[1][0] += xv.y * wv.x; acc[1][1] += xv.y * wv.y; acc[1][2] += xv.y * wv.z; acc[1][3] += xv.y * wv.w;
        acc[2][0] += xv.z * wv.x; acc[2][1] += xv.z * wv.y; acc[2][2] += xv.z * wv.z; acc[2][3] += xv.z * wv.w;
        acc[3][0] += xv.w * wv.x; acc[3][1] += xv.w * wv.y; acc[3][2] += xv.w * wv.z; acc[3][3] += xv.w * wv.w;
    }
#pragma unroll
    for (int i = 0; i < 4; ++i) {
        int rr = row0 + ty * 4 + i;
        if (rr < n) {
            float s = dk[rr];
            uint2 o;
            o.x = (unsigned)f2bf(acc[i][0] * s) | ((unsigned)f2bf(acc[i][1] * s) << 16);
            o.y = (unsigned)f2bf(acc[i][2] * s) | ((unsigned)f2bf(acc[i][3] * s) << 16);
            *(uint2*)&y2b[(size_t)rr * D_OUT + tx * 4] = o;
        }
    }
}

// ---------------------------------------------------------------------------
// SpMM: one wave per row, lane = output feature. bf16 gather table (halved
// L2-miss traffic vs f32). out[i] = dk[i]*(y2[i] + sum_e y2[col_e]) + b
// ---------------------------------------------------------------------------
__global__ __launch_bounds__(256) void k_spmm(
        const int* __restrict__ rowptr, const int* __restrict__ colidx,
        const unsigned short* __restrict__ y2b, const float* __restrict__ dk,
        const float* __restrict__ bias, float* __restrict__ out, int n, int span) {
    const int g    = blockIdx.x & (NGRP - 1);
    const int wv   = threadIdx.x >> 6;
    const int lane = threadIdx.x & 63;
    const int row  = g * span + (blockIdx.x >> 3) * 4 + wv;
    const int hi   = min((g + 1) * span, n);
    if (row >= hi) return;

    int start = rowptr[row];
    int end   = rowptr[row + 1];
    float acc = bf2f(y2b[(size_t)row * D_OUT + lane]);   // self loop term

    int e = start;
    for (; e + 8 <= end; e += 8) {
        int c0 = colidx[e + 0], c1 = colidx[e + 1], c2 = colidx[e + 2], c3 = colidx[e + 3];
        int c4 = colidx[e + 4], c5 = colidx[e + 5], c6 = colidx[e + 6], c7 = colidx[e + 7];
        float v0 = bf2f(y2b[(size_t)c0 * D_OUT + lane]);
        float v1 = bf2f(y2b[(size_t)c1 * D_OUT + lane]);
        float v2 = bf2f(y2b[(size_t)c2 * D_OUT + lane]);
        float v3 = bf2f(y2b[(size_t)c3 * D_OUT + lane]);
        float v4 = bf2f(y2b[(size_t)c4 * D_OUT + lane]);
        float v5 = bf2f(y2b[(size_t)c5 * D_OUT + lane]);
        float v6 = bf2f(y2b[(size_t)c6 * D_OUT + lane]);
        float v7 = bf2f(y2b[(size_t)c7 * D_OUT + lane]);
        acc += ((v0 + v1) + (v2 + v3)) + ((v4 + v5) + (v6 + v7));
    }
    for (; e < end; ++e)
        acc += bf2f(y2b[(size_t)colidx[e] * D_OUT + lane]);

    out[(size_t)row * D_OUT + lane] = dk[row] * acc + bias[lane];
}

// ---------------------------------------------------------------------------
extern "C" void kernel_launch(void* const* d_in, const int* in_sizes, int n_in,
                              void* d_out, int out_size, void* d_ws, size_t ws_size,
                              hipStream_t stream) {
    const float* x    = (const float*)d_in[0];
    const void*  ei   = d_in[1];
    const float* W    = (const float*)d_in[2];
    const float* b    = (const float*)d_in[3];
    const int*   kptr = (const int*)d_in[4];

    const int       n = in_sizes[0] / D_IN;            // 100000
    const long long E = (long long)in_sizes[1] / 2;    // 3200000
    const int    span = (n + NGRP - 1) / NGRP;         // 12500 (<= 1<<SHIFT)
    const int     nsb = (span + SBROWS - 1) / SBROWS;  // 66 (<= NSB_MAX)
    const int    cap1 = (int)(E / NGRP) + 65536;
    const unsigned long long inv = ((1ULL << 40) + span - 1) / (unsigned long long)span;

    char* ws = (char*)d_ws;
    size_t off = 0;
    auto alloc = [&](size_t bytes) -> void* {
        void* p = ws + off;
        off += (bytes + 255) & ~(size_t)255;
        return p;
    };
    int*          flag   = (int*)alloc(4);
    int*          gcur   = (int*)alloc(NGRP * 16 * 4);
    int*          gcur2  = (int*)alloc((size_t)NGRP * nsb * 16 * 4);
    int*          sbbase = (int*)alloc((size_t)NGRP * nsb * 4);
    int*          rowptr = (int*)alloc(((size_t)n + 1) * 4);
    float*        dk     = (float*)alloc((size_t)n * 4);
    // parts1 (8*cap1*4 = 14.9 MB); colidx aliases it (parts1 dead after split2)
    size_t p1_bytes = (size_t)NGRP * cap1 * 4;
    size_t ci_bytes = (size_t)E * 4;
    unsigned int* parts1 = (unsigned int*)alloc(p1_bytes > ci_bytes ? p1_bytes : ci_bytes);
    int*          colidx = (int*)parts1;
    // parts2 (528*CAP2*4 = 17.3 MB); y2b (bf16, 12.8 MB) aliases it (parts2 dead after cidx)
    size_t p2_bytes = (size_t)NGRP * nsb * CAP2 * 4;
    size_t y2_bytes = (size_t)n * D_OUT * 2;
    unsigned int*   parts2 = (unsigned int*)alloc(p2_bytes > y2_bytes ? p2_bytes : y2_bytes);
    unsigned short* y2b    = (unsigned short*)parts2;
    (void)ws_size; (void)n_in; (void)out_size;

    hipMemsetAsync(gcur, 0, NGRP * 16 * 4, stream);
    hipMemsetAsync(gcur2, 0, (size_t)NGRP * nsb * 16 * 4, stream);
    k_detect<<<1, 256, 0, stream>>>((const unsigned int*)ei, flag);
    k_split<<<1024, 256, 0, stream>>>(ei, flag, gcur, parts1, E, span, inv, cap1);
    k_split2<<<512, 256, 0, stream>>>(parts1, gcur, gcur2, parts2, cap1, nsb);
    k_scan_sb<<<1, 256, 0, stream>>>(gcur2, sbbase, rowptr, NGRP * nsb, n);
    k_cidx<<<NGRP * nsb, 256, 0, stream>>>(parts2, gcur2, sbbase, rowptr, dk,
                                           kptr, colidx, span, nsb, n);
    k_gemm<<<(n + 63) / 64, 256, 0, stream>>>(x, W, dk, y2b, n);
    k_spmm<<<NGRP * ((span + 3) / 4), 256, 0, stream>>>(rowptr, colidx, y2b, dk, b,
                                                        (float*)d_out, n, span);
}

// Round 8
// 190.820 us; speedup vs baseline: 2.4451x; 1.1248x over previous
//
#include <hip/hip_runtime.h>
#include <hip/hip_bf16.h>
#include <math.h>

#define D_IN   128
#define D_OUT  64
#define NGRP   8            // row-range groups, matched to 8 XCDs via blockIdx&7
#define SHIFT  14           // local-row bits in packed pair (span <= 16384)
#define PMASK  ((1u << SHIFT) - 1u)
#define SBROWS 192          // rows per sub-bucket
#define CAP2   8192         // max edges per sub-bucket
#define NSB_MAX 128

__device__ __forceinline__ unsigned short f2bf(float f) {   // RTNE f32 -> bf16
    unsigned u = __float_as_uint(f);
    return (unsigned short)((u + 0x7FFFu + ((u >> 16) & 1u)) >> 16);
}
__device__ __forceinline__ float bflo(unsigned v) { return __uint_as_float(v << 16); }
__device__ __forceinline__ float bfhi(unsigned v) { return __uint_as_float(v & 0xFFFF0000u); }

// ---------------------------------------------------------------------------
// Edge-index dtype detection (int64 vs int32, little-endian high-word probe).
// ---------------------------------------------------------------------------
__global__ void k_detect(const unsigned int* __restrict__ u, int* __restrict__ flag) {
    __shared__ int nonzero;
    if (threadIdx.x == 0) nonzero = 0;
    __syncthreads();
    if (u[2 * threadIdx.x + 1] != 0u) atomicOr(&nonzero, 1);
    __syncthreads();
    if (threadIdx.x == 0) *flag = (nonzero == 0) ? 1 : 0;  // 1 => int64
}

__device__ __forceinline__ int edge_val(const void* ei, int is64, long long idx) {
    return is64 ? (int)((const long long*)ei)[idx] : ((const int*)ei)[idx];
}

// ---------------------------------------------------------------------------
// Pass 1 multisplit: edges -> 8 row-range groups, pair = (col<<SHIFT)|(r-g*span).
// ---------------------------------------------------------------------------
__global__ __launch_bounds__(256) void k_split(const void* __restrict__ ei,
        const int* __restrict__ flag, int* __restrict__ gcur,
        unsigned int* __restrict__ parts1, long long E, int span,
        unsigned long long inv, int cap1) {
    __shared__ int scnt[NGRP];
    __shared__ int sbase[NGRP];
    const int is64 = *flag;
    const int tid  = threadIdx.x;
    const long long tile = 4096;

    for (long long t0 = (long long)blockIdx.x * tile; t0 < E;
         t0 += (long long)gridDim.x * tile) {
        if (tid < NGRP) scnt[tid] = 0;
        __syncthreads();
        int g16[16], rk16[16];
        unsigned int q16[16];
#pragma unroll
        for (int j = 0; j < 16; ++j) {
            long long e = t0 + (long long)j * 256 + tid;
            if (e < E) {
                int r = edge_val(ei, is64, e);
                int c = edge_val(ei, is64, E + e);
                int g = (int)(((unsigned long long)(unsigned int)r * inv) >> 40);
                while (r >= (g + 1) * span) ++g;
                while (r < g * span) --g;
                g16[j] = g;
                q16[j] = ((unsigned int)c << SHIFT) | (unsigned int)(r - g * span);
                rk16[j] = atomicAdd(&scnt[g], 1);
            } else g16[j] = -1;
        }
        __syncthreads();
        if (tid < NGRP && scnt[tid] > 0)
            sbase[tid] = atomicAdd(&gcur[tid * 16], scnt[tid]);
        __syncthreads();
#pragma unroll
        for (int j = 0; j < 16; ++j) {
            if (g16[j] >= 0) {
                int pos = sbase[g16[j]] + rk16[j];
                if (pos < cap1)
                    parts1[(size_t)g16[j] * cap1 + pos] = q16[j];
            }
        }
        __syncthreads();
    }
}

// ---------------------------------------------------------------------------
// Pass 2 multisplit: group partition -> sub-buckets of SBROWS rows.
// ---------------------------------------------------------------------------
__global__ __launch_bounds__(256) void k_split2(const unsigned int* __restrict__ parts1,
        const int* __restrict__ gcur, int* __restrict__ gcur2,
        unsigned int* __restrict__ parts2, int cap1, int nsb) {
    __shared__ int scnt[NSB_MAX];
    __shared__ int sbase[NSB_MAX];
    const int g   = blockIdx.x & (NGRP - 1);
    const int sz  = min(gcur[g * 16], cap1);
    const unsigned int* p = parts1 + (size_t)g * cap1;
    const int tid = threadIdx.x;
    const int tile = 4096;

    for (int t0 = (blockIdx.x >> 3) * tile; t0 < sz; t0 += (gridDim.x >> 3) * tile) {
        if (tid < nsb) scnt[tid] = 0;
        __syncthreads();
        int s16[16], rk16[16];
        unsigned int q16[16];
#pragma unroll
        for (int j = 0; j < 16; ++j) {
            int i = t0 + j * 256 + tid;
            if (i < sz) {
                unsigned int q = p[i];
                int sb = (int)(q & PMASK) / SBROWS;
                s16[j] = sb; q16[j] = q;
                rk16[j] = atomicAdd(&scnt[sb], 1);
            } else s16[j] = -1;
        }
        __syncthreads();
        if (tid < nsb && scnt[tid] > 0)
            sbase[tid] = atomicAdd(&gcur2[(g * nsb + tid) * 16], scnt[tid]);
        __syncthreads();
#pragma unroll
        for (int j = 0; j < 16; ++j) {
            if (s16[j] >= 0) {
                int pos = sbase[s16[j]] + rk16[j];
                if (pos < CAP2)
                    parts2[(size_t)(g * nsb + s16[j]) * CAP2 + pos] = q16[j];
            }
        }
        __syncthreads();
    }
}

// ---------------------------------------------------------------------------
// Scan sub-bucket sizes -> colidx base per sub-bucket. Capacity-based
// spacing = size + 3*SBROWS (worst-case per-row pad to multiple of 4).
// Row ends come from the explicit rowend[] array (NOT rowptr[row+1]).
// ---------------------------------------------------------------------------
__global__ void k_scan_sb(const int* __restrict__ gcur2, int* __restrict__ sbbase,
                          int total_sb) {
    __shared__ int sm[256];
    const int tid = threadIdx.x;
    int v[3]; int t = 0;
#pragma unroll
    for (int j = 0; j < 3; ++j) {
        int idx = tid * 3 + j;
        v[j] = (idx < total_sb) ? min(gcur2[idx * 16], CAP2) + 3 * SBROWS : 0;
        t += v[j];
    }
    sm[tid] = t; __syncthreads();
    for (int o = 1; o < 256; o <<= 1) {
        int a = (tid >= o) ? sm[tid - o] : 0;
        __syncthreads();
        sm[tid] += a;
        __syncthreads();
    }
    int run = sm[tid] - t;
#pragma unroll
    for (int j = 0; j < 3; ++j) {
        int idx = tid * 3 + j;
        if (idx < total_sb) { sbbase[idx] = run; run += v[j]; }
    }
}

// ---------------------------------------------------------------------------
// CSR-ify one sub-bucket in LDS. Each row's entry list is padded to a
// multiple of 4 with dummy column n (zero row in y2b). Emits rowptr (start),
// rowend (start + padded count), dk, and sequential colidx.
// ---------------------------------------------------------------------------
__global__ __launch_bounds__(256) void k_cidx(const unsigned int* __restrict__ parts2,
        const int* __restrict__ gcur2, const int* __restrict__ sbbase,
        int* __restrict__ rowptr, int* __restrict__ rowend,
        float* __restrict__ dk, const int* __restrict__ kptr,
        int* __restrict__ colidx, int span, int nsb, int n) {
    __shared__ int scnt[256];
    __shared__ int ssum[256];
    __shared__ int scur[256];
    __shared__ unsigned int clds[CAP2];    // 32 KB

    const int g   = blockIdx.x & (NGRP - 1);
    const int sb  = blockIdx.x >> 3;
    if (sb >= nsb) return;
    const int sbi = g * nsb + sb;
    const int sz  = min(gcur2[sbi * 16], CAP2);
    const unsigned int* p = parts2 + (size_t)sbi * CAP2;
    const int row0l = sb * SBROWS;
    const int row0g = g * span + row0l;
    if (row0g >= n) return;
    const int rows_here = min(min(SBROWS, span - row0l), n - row0g);
    const int tid = threadIdx.x;
    const int sbb = sbbase[sbi];

    scnt[tid] = 0;
    __syncthreads();

    unsigned int q[32]; int rl[32];
#pragma unroll
    for (int j = 0; j < 32; ++j) {
        int i = j * 256 + tid;
        if (i < sz) {
            q[j]  = p[i];
            rl[j] = (int)(q[j] & PMASK) - row0l;
            atomicAdd(&scnt[rl[j]], 1);
        }
    }
    __syncthreads();

    // padded counts (multiple of 4), inclusive scan
    int truec = scnt[tid];
    int padc  = (tid < rows_here) ? ((truec + 3) & ~3) : 0;
    ssum[tid] = padc;
    __syncthreads();
    for (int o = 1; o < 256; o <<= 1) {
        int a = (tid >= o) ? ssum[tid - o] : 0;
        __syncthreads();
        ssum[tid] += a;
        __syncthreads();
    }
    int excl = ssum[tid] - padc;
    scur[tid] = excl;
    if (tid < rows_here) {
        rowptr[row0g + tid] = sbb + excl;
        rowend[row0g + tid] = sbb + ssum[tid];   // exact padded end, mult of 4
        int kk = kptr[0];
        if (kk < 0 || kk > 1000) {
            float kf = ((const float*)kptr)[0];
            kk = (kf > 0.f && kf < 1000.f) ? (int)(kf + 0.5f) : 2;
        }
        float deg  = (float)(truec + 1);
        float dinv = 1.0f / sqrtf(deg);
        float v = 1.0f;
        for (int t = 0; t < kk; ++t) v *= dinv;
        dk[row0g + tid] = v;
        // fill pad slots with dummy col n (zero row)
        for (int j = truec; j < padc; ++j) {
            int pos = excl + j;
            if (pos < CAP2) clds[pos] = (unsigned int)n;
        }
    }
    __syncthreads();

#pragma unroll
    for (int j = 0; j < 32; ++j) {
        int i = j * 256 + tid;
        if (i < sz) {
            int pos = atomicAdd(&scur[rl[j]], 1);
            if (pos < CAP2) clds[pos] = q[j] >> SHIFT;
        }
    }
    __syncthreads();

    const int ptotal = min(ssum[255], CAP2);
#pragma unroll
    for (int j = 0; j < 32; ++j) {
        int i = j * 256 + tid;
        if (i < ptotal) colidx[sbb + i] = (int)clds[i];
    }
}

// ---------------------------------------------------------------------------
// y2b[r][:] = bf16( dk[r] * (x[r] @ W^T) ). 64 rows/block, 4x4 micro-tile.
// ---------------------------------------------------------------------------
__global__ __launch_bounds__(256) void k_gemm(const float* __restrict__ x,
        const float* __restrict__ W, const float* __restrict__ dk,
        unsigned short* __restrict__ y2b, int n) {
    __shared__ float Wt[D_IN][D_OUT];   // 32 KB
    __shared__ float xsT[D_IN][64];     // 32 KB
    const int tid = threadIdx.x;
    const int row0 = blockIdx.x * 64;

    {
        const int c = tid & 63;
        const int dblk = (tid >> 6) * 32;
        const float* wr = &W[c * D_IN + dblk];
#pragma unroll
        for (int j = 0; j < 32; j += 4) {
            float4 w4 = *(const float4*)(wr + j);
            Wt[dblk + j + 0][c] = w4.x;
            Wt[dblk + j + 1][c] = w4.y;
            Wt[dblk + j + 2][c] = w4.z;
            Wt[dblk + j + 3][c] = w4.w;
        }
    }
    {
        const int r = tid & 63;
        const int h = tid >> 6;
        const int grow = row0 + r;
        const float* xr = &x[(size_t)grow * D_IN + h * 32];
#pragma unroll
        for (int j = 0; j < 32; j += 4) {
            float4 v = (grow < n) ? *(const float4*)(xr + j)
                                  : make_float4(0.f, 0.f, 0.f, 0.f);
            xsT[h * 32 + j + 0][r] = v.x;
            xsT[h * 32 + j + 1][r] = v.y;
            xsT[h * 32 + j + 2][r] = v.z;
            xsT[h * 32 + j + 3][r] = v.w;
        }
    }
    __syncthreads();

    const int tx = tid & 15;
    const int ty = tid >> 4;
    float acc[4][4] = {};
#pragma unroll 8
    for (int d = 0; d < D_IN; ++d) {
        float4 wv = *(const float4*)&Wt[d][tx * 4];
        float4 xv = *(const float4*)&xsT[d][ty * 4];
        acc[0][0] += xv.x * wv.x; acc[0][1] += xv.x * wv.y; acc[0][2] += xv.x * wv.z; acc[0][3] += xv.x * wv.w;
        acc[1][0] += xv.y * wv.x; acc[1][1] += xv.y * wv.y; acc[1][2] += xv.y * wv.z; acc[1][3] += xv.y * wv.w;
        acc[2][0] += xv.z * wv.x; acc[2][1] += xv.z * wv.y; acc[2][2] += xv.z * wv.z; acc[2][3] += xv.z * wv.w;
        acc[3][0] += xv.w * wv.x; acc[3][1] += xv.w * wv.y; acc[3][2] += xv.w * wv.z; acc[3][3] += xv.w * wv.w;
    }
#pragma unroll
    for (int i = 0; i < 4; ++i) {
        int rr = row0 + ty * 4 + i;
        if (rr < n) {
            float s = dk[rr];
            uint2 o;
            o.x = (unsigned)f2bf(acc[i][0] * s) | ((unsigned)f2bf(acc[i][1] * s) << 16);
            o.y = (unsigned)f2bf(acc[i][2] * s) | ((unsigned)f2bf(acc[i][3] * s) << 16);
            *(uint2*)&y2b[(size_t)rr * D_OUT + tx * 4] = o;
        }
    }
}

// ---------------------------------------------------------------------------
// SpMM: one wave per row; lane = (edge-slot grp = lane>>4, feat-quad fl =
// lane&15). Each step gathers 4 edges x 4 bf16 features per lane (uint2,
// 8B/lane; 16 lanes cover a 128B y2b row). Rows padded to multiple of 4
// edges (dummy col n -> zero row). Butterfly-reduce edge slots at the end.
// ---------------------------------------------------------------------------
__global__ __launch_bounds__(256) void k_spmm(
        const int* __restrict__ rowptr, const int* __restrict__ rowend,
        const int* __restrict__ colidx,
        const unsigned short* __restrict__ y2b, const float* __restrict__ dk,
        const float* __restrict__ bias, float* __restrict__ out, int n, int span) {
    const int g    = blockIdx.x & (NGRP - 1);
    const int wv   = threadIdx.x >> 6;
    const int lane = threadIdx.x & 63;
    const int grp  = lane >> 4;    // edge slot 0..3
    const int fl   = lane & 15;    // feature quad: feats 4*fl .. 4*fl+3
    const int row  = g * span + (blockIdx.x >> 3) * 4 + wv;
    const int hi   = min((g + 1) * span, n);
    if (row >= hi) return;

    const int start = rowptr[row];
    const int end   = rowend[row];    // start + padded count (mult of 4)

    float a0 = 0.f, a1 = 0.f, a2 = 0.f, a3 = 0.f;
    int e = start;
    for (; e + 8 <= end; e += 8) {
        int ca = colidx[e + grp];
        int cb = colidx[e + 4 + grp];
        uint2 va = *(const uint2*)&y2b[(size_t)ca * D_OUT + fl * 4];
        uint2 vb = *(const uint2*)&y2b[(size_t)cb * D_OUT + fl * 4];
        a0 += bflo(va.x); a1 += bfhi(va.x); a2 += bflo(va.y); a3 += bfhi(va.y);
        a0 += bflo(vb.x); a1 += bfhi(vb.x); a2 += bflo(vb.y); a3 += bfhi(vb.y);
    }
    if (e < end) {   // exactly 4 remain (padded)
        int c = colidx[e + grp];
        uint2 v = *(const uint2*)&y2b[(size_t)c * D_OUT + fl * 4];
        a0 += bflo(v.x); a1 += bfhi(v.x); a2 += bflo(v.y); a3 += bfhi(v.y);
    }

    // reduce the 4 edge slots (butterfly over lane bits 4,5)
    a0 += __shfl_xor(a0, 16); a1 += __shfl_xor(a1, 16);
    a2 += __shfl_xor(a2, 16); a3 += __shfl_xor(a3, 16);
    a0 += __shfl_xor(a0, 32); a1 += __shfl_xor(a1, 32);
    a2 += __shfl_xor(a2, 32); a3 += __shfl_xor(a3, 32);

    if (grp == 0) {
        uint2 sv = *(const uint2*)&y2b[(size_t)row * D_OUT + fl * 4];  // self loop
        a0 += bflo(sv.x); a1 += bfhi(sv.x); a2 += bflo(sv.y); a3 += bfhi(sv.y);
        float s = dk[row];
        float4 bb = *(const float4*)&bias[fl * 4];
        float4 o = make_float4(s * a0 + bb.x, s * a1 + bb.y,
                               s * a2 + bb.z, s * a3 + bb.w);
        *(float4*)&out[(size_t)row * D_OUT + fl * 4] = o;
    }
}

// ---------------------------------------------------------------------------
extern "C" void kernel_launch(void* const* d_in, const int* in_sizes, int n_in,
                              void* d_out, int out_size, void* d_ws, size_t ws_size,
                              hipStream_t stream) {
    const float* x    = (const float*)d_in[0];
    const void*  ei   = d_in[1];
    const float* W    = (const float*)d_in[2];
    const float* b    = (const float*)d_in[3];
    const int*   kptr = (const int*)d_in[4];

    const int       n = in_sizes[0] / D_IN;            // 100000
    const long long E = (long long)in_sizes[1] / 2;    // 3200000
    const int    span = (n + NGRP - 1) / NGRP;         // 12500 (<= 1<<SHIFT)
    const int     nsb = (span + SBROWS - 1) / SBROWS;  // 66 (<= NSB_MAX)
    const int    cap1 = (int)(E / NGRP) + 65536;
    const unsigned long long inv = ((1ULL << 40) + span - 1) / (unsigned long long)span;

    char* ws = (char*)d_ws;
    size_t off = 0;
    auto alloc = [&](size_t bytes) -> void* {
        void* p = ws + off;
        off += (bytes + 255) & ~(size_t)255;
        return p;
    };
    int*          flag   = (int*)alloc(4);
    int*          gcur   = (int*)alloc(NGRP * 16 * 4);
    int*          gcur2  = (int*)alloc((size_t)NGRP * nsb * 16 * 4);
    int*          sbbase = (int*)alloc((size_t)NGRP * nsb * 4);
    int*          rowptr = (int*)alloc((size_t)n * 4);
    int*          rowend = (int*)alloc((size_t)n * 4);
    float*        dk     = (float*)alloc((size_t)n * 4);
    // parts1 (8*cap1*4 = 14.9 MB); colidx aliases it (needs E + 528*576 ints = 14.0 MB)
    size_t p1_bytes = (size_t)NGRP * cap1 * 4;
    size_t ci_bytes = ((size_t)E + (size_t)NGRP * nsb * 3 * SBROWS) * 4;
    unsigned int* parts1 = (unsigned int*)alloc(p1_bytes > ci_bytes ? p1_bytes : ci_bytes);
    int*          colidx = (int*)parts1;
    // parts2 (528*CAP2*4 = 17.3 MB); y2b (bf16, n+1 rows) aliases it
    size_t p2_bytes = (size_t)NGRP * nsb * CAP2 * 4;
    size_t y2_bytes = ((size_t)n + 1) * D_OUT * 2;
    unsigned int*   parts2 = (unsigned int*)alloc(p2_bytes > y2_bytes ? p2_bytes : y2_bytes);
    unsigned short* y2b    = (unsigned short*)parts2;
    (void)ws_size; (void)n_in; (void)out_size;

    hipMemsetAsync(gcur, 0, NGRP * 16 * 4, stream);
    hipMemsetAsync(gcur2, 0, (size_t)NGRP * nsb * 16 * 4, stream);
    k_detect<<<1, 256, 0, stream>>>((const unsigned int*)ei, flag);
    k_split<<<1024, 256, 0, stream>>>(ei, flag, gcur, parts1, E, span, inv, cap1);
    k_split2<<<512, 256, 0, stream>>>(parts1, gcur, gcur2, parts2, cap1, nsb);
    k_scan_sb<<<1, 256, 0, stream>>>(gcur2, sbbase, NGRP * nsb);
    k_cidx<<<NGRP * nsb, 256, 0, stream>>>(parts2, gcur2, sbbase, rowptr, rowend,
                                           dk, kptr, colidx, span, nsb, n);
    // zero row n of y2b (gather target for pad columns)
    hipMemsetAsync(y2b + (size_t)n * D_OUT, 0, D_OUT * 2, stream);
    k_gemm<<<(n + 63) / 64, 256, 0, stream>>>(x, W, dk, y2b, n);
    k_spmm<<<NGRP * ((span + 3) / 4), 256, 0, stream>>>(rowptr, rowend, colidx,
                                                        y2b, dk, b,
                                                        (float*)d_out, n, span);
}

// Round 9
// 153.428 us; speedup vs baseline: 3.0410x; 1.2437x over previous
//
#include <hip/hip_runtime.h>
#include <hip/hip_bf16.h>
#include <math.h>

#define D_IN   128
#define D_OUT  64
#define SHIFT  8            // local-row bits in packed pair (SBROWS <= 256)
#define PMASK  ((1u << SHIFT) - 1u)
#define SBROWS 192          // rows per bucket
#define NBPAD  528          // padded bucket count (>= nb=521), per-rep stride
#define CAPR   1024         // capacity per (bucket, xcd-replica); mean 758, +10 sigma
#define CLDS_N 9536         // bucket edges (<=8192) + worst-case pad (1344)

__device__ __forceinline__ unsigned short f2bf(float f) {   // RTNE f32 -> bf16
    unsigned u = __float_as_uint(f);
    return (unsigned short)((u + 0x7FFFu + ((u >> 16) & 1u)) >> 16);
}
__device__ __forceinline__ float bflo(unsigned v) { return __uint_as_float(v << 16); }
__device__ __forceinline__ float bfhi(unsigned v) { return __uint_as_float(v & 0xFFFF0000u); }

// ---------------------------------------------------------------------------
// Edge-index dtype detection (int64 vs int32, little-endian high-word probe).
// ---------------------------------------------------------------------------
__global__ void k_detect(const unsigned int* __restrict__ u, int* __restrict__ flag) {
    __shared__ int nonzero;
    if (threadIdx.x == 0) nonzero = 0;
    __syncthreads();
    if (u[2 * threadIdx.x + 1] != 0u) atomicOr(&nonzero, 1);
    __syncthreads();
    if (threadIdx.x == 0) *flag = (nonzero == 0) ? 1 : 0;  // 1 => int64
}

__device__ __forceinline__ int edge_val(const void* ei, int is64, long long idx) {
    return is64 ? (int)((const long long*)ei)[idx] : ((const int*)ei)[idx];
}

// ---------------------------------------------------------------------------
// Single-pass multisplit: edges -> 521 buckets of SBROWS rows, with 8
// XCD-private replica segments per bucket (rep = blockIdx&7). Tail lines of
// each replica region are written by one XCD only -> they coalesce in that
// XCD's L2 (this is what makes one-level 521-way binning viable; the R2
// failure was cross-XCD tail-line sharing). LDS-rank per 4096-edge tile.
// pair = (col << 8) | (r - bucket*SBROWS).
// ---------------------------------------------------------------------------
__global__ __launch_bounds__(256) void k_split3(const void* __restrict__ ei,
        const int* __restrict__ flag, int* __restrict__ gcur,
        unsigned int* __restrict__ parts, long long E, int nb) {
    __shared__ int scnt[544];
    __shared__ int sbase[544];
    const int is64 = *flag;
    const int tid  = threadIdx.x;
    const int rep  = blockIdx.x & 7;
    const long long tile = 4096;

    for (long long t0 = (long long)blockIdx.x * tile; t0 < E;
         t0 += (long long)gridDim.x * tile) {
        for (int i = tid; i < nb; i += 256) scnt[i] = 0;
        __syncthreads();
        int sb16[16], rk16[16];
        unsigned int q16[16];
#pragma unroll
        for (int j = 0; j < 16; ++j) {
            long long e = t0 + (long long)j * 256 + tid;
            if (e < E) {
                int r = edge_val(ei, is64, e);
                int c = edge_val(ei, is64, E + e);
                unsigned sb = (unsigned)r / SBROWS;   // const divisor -> magic mul
                sb16[j] = (int)sb;
                q16[j]  = ((unsigned int)c << SHIFT) | (unsigned int)(r - sb * SBROWS);
                rk16[j] = atomicAdd(&scnt[sb], 1);
            } else sb16[j] = -1;
        }
        __syncthreads();
        for (int i = tid; i < nb; i += 256)
            if (scnt[i] > 0) sbase[i] = atomicAdd(&gcur[rep * NBPAD + i], scnt[i]);
        __syncthreads();
#pragma unroll
        for (int j = 0; j < 16; ++j) {
            if (sb16[j] >= 0) {
                int pos = sbase[sb16[j]] + rk16[j];
                if (pos < CAPR)
                    parts[((size_t)sb16[j] * 8 + rep) * CAPR + pos] = q16[j];
            }
        }
        __syncthreads();
    }
}

// ---------------------------------------------------------------------------
// Scan bucket sizes (sum of 8 replicas) -> colidx base per bucket.
// Capacity spacing = size + 7*SBROWS (worst-case pad-to-8 per row).
// ---------------------------------------------------------------------------
__global__ void k_scan_sb(const int* __restrict__ gcur, int* __restrict__ sbbase,
                          int nb) {
    __shared__ int sm[256];
    const int tid = threadIdx.x;
    int v[3]; int t = 0;
#pragma unroll
    for (int j = 0; j < 3; ++j) {
        int idx = tid * 3 + j;
        int s = 0;
        if (idx < nb) {
#pragma unroll
            for (int rep = 0; rep < 8; ++rep)
                s += min(gcur[rep * NBPAD + idx], CAPR);
            s += 7 * SBROWS;
        }
        v[j] = s; t += s;
    }
    sm[tid] = t; __syncthreads();
    for (int o = 1; o < 256; o <<= 1) {
        int a = (tid >= o) ? sm[tid - o] : 0;
        __syncthreads();
        sm[tid] += a;
        __syncthreads();
    }
    int run = sm[tid] - t;
#pragma unroll
    for (int j = 0; j < 3; ++j) {
        int idx = tid * 3 + j;
        if (idx < nb) { sbbase[idx] = run; run += v[j]; }
    }
}

// ---------------------------------------------------------------------------
// CSR-ify one bucket in LDS from its 8 replica segments. Rows padded to a
// multiple of 8 with dummy column n (zero row in y2b). Emits rowptr (start),
// rowend (start + padded count), dk = (deg+1)^(-k/2), sequential colidx.
// ---------------------------------------------------------------------------
__global__ __launch_bounds__(256) void k_cidx(const unsigned int* __restrict__ parts,
        const int* __restrict__ gcur, const int* __restrict__ sbbase,
        int* __restrict__ rowptr, int* __restrict__ rowend,
        float* __restrict__ dk, const int* __restrict__ kptr,
        int* __restrict__ colidx, int nb, int n) {
    __shared__ int scnt[256];
    __shared__ int ssum[256];
    __shared__ int scur[256];
    __shared__ unsigned int clds[CLDS_N];   // 37.3 KB

    const int b = blockIdx.x;
    if (b >= nb) return;
    const int row0 = b * SBROWS;
    if (row0 >= n) return;
    const int rows_here = min(SBROWS, n - row0);
    const int tid = threadIdx.x;
    const int sbb = sbbase[b];

    int szs[8];
#pragma unroll
    for (int rep = 0; rep < 8; ++rep) szs[rep] = min(gcur[rep * NBPAD + b], CAPR);

    scnt[tid] = 0;
    __syncthreads();

    unsigned int q[32]; int rl[32];
#pragma unroll
    for (int rep = 0; rep < 8; ++rep) {
        const unsigned int* p = parts + ((size_t)b * 8 + rep) * CAPR;
#pragma unroll
        for (int j = 0; j < 4; ++j) {
            const int idx = rep * 4 + j;
            const int i = j * 256 + tid;
            if (i < szs[rep]) {
                q[idx]  = p[i];
                rl[idx] = (int)(q[idx] & PMASK);
                atomicAdd(&scnt[rl[idx]], 1);
            } else rl[idx] = -1;
        }
    }
    __syncthreads();

    // padded counts (multiple of 8), inclusive scan
    int truec = scnt[tid];
    int padc  = (tid < rows_here) ? ((truec + 7) & ~7) : 0;
    ssum[tid] = padc;
    __syncthreads();
    for (int o = 1; o < 256; o <<= 1) {
        int a = (tid >= o) ? ssum[tid - o] : 0;
        __syncthreads();
        ssum[tid] += a;
        __syncthreads();
    }
    int excl = ssum[tid] - padc;
    scur[tid] = excl;
    if (tid < rows_here) {
        rowptr[row0 + tid] = sbb + excl;
        rowend[row0 + tid] = sbb + ssum[tid];   // start + padded count (mult 8)
        int kk = kptr[0];
        if (kk < 0 || kk > 1000) {
            float kf = ((const float*)kptr)[0];
            kk = (kf > 0.f && kf < 1000.f) ? (int)(kf + 0.5f) : 2;
        }
        float deg  = (float)(truec + 1);
        float dinv = 1.0f / sqrtf(deg);
        float v = 1.0f;
        for (int t = 0; t < kk; ++t) v *= dinv;
        dk[row0 + tid] = v;
        for (int j = truec; j < padc; ++j) {    // pad -> dummy col n (zero row)
            int pos = excl + j;
            if (pos < CLDS_N) clds[pos] = (unsigned int)n;
        }
    }
    __syncthreads();

#pragma unroll
    for (int rep = 0; rep < 8; ++rep) {
#pragma unroll
        for (int j = 0; j < 4; ++j) {
            const int idx = rep * 4 + j;
            if (rl[idx] >= 0) {
                int pos = atomicAdd(&scur[rl[idx]], 1);
                if (pos < CLDS_N) clds[pos] = q[idx] >> SHIFT;
            }
        }
    }
    __syncthreads();

    const int ptotal = min(ssum[255], CLDS_N);
    for (int i = tid; i < ptotal; i += 256)     // sequential write-out
        colidx[sbb + i] = (int)clds[i];
}

// ---------------------------------------------------------------------------
// y2b[r][:] = bf16( dk[r] * (x[r] @ W^T) ). 64 rows/block, 4x4 micro-tile.
// ---------------------------------------------------------------------------
__global__ __launch_bounds__(256) void k_gemm(const float* __restrict__ x,
        const float* __restrict__ W, const float* __restrict__ dk,
        unsigned short* __restrict__ y2b, int n) {
    __shared__ float Wt[D_IN][D_OUT];   // 32 KB
    __shared__ float xsT[D_IN][64];     // 32 KB
    const int tid = threadIdx.x;
    const int row0 = blockIdx.x * 64;

    {
        const int c = tid & 63;
        const int dblk = (tid >> 6) * 32;
        const float* wr = &W[c * D_IN + dblk];
#pragma unroll
        for (int j = 0; j < 32; j += 4) {
            float4 w4 = *(const float4*)(wr + j);
            Wt[dblk + j + 0][c] = w4.x;
            Wt[dblk + j + 1][c] = w4.y;
            Wt[dblk + j + 2][c] = w4.z;
            Wt[dblk + j + 3][c] = w4.w;
        }
    }
    {
        const int r = tid & 63;
        const int h = tid >> 6;
        const int grow = row0 + r;
        const float* xr = &x[(size_t)grow * D_IN + h * 32];
#pragma unroll
        for (int j = 0; j < 32; j += 4) {
            float4 v = (grow < n) ? *(const float4*)(xr + j)
                                  : make_float4(0.f, 0.f, 0.f, 0.f);
            xsT[h * 32 + j + 0][r] = v.x;
            xsT[h * 32 + j + 1][r] = v.y;
            xsT[h * 32 + j + 2][r] = v.z;
            xsT[h * 32 + j + 3][r] = v.w;
        }
    }
    __syncthreads();

    const int tx = tid & 15;
    const int ty = tid >> 4;
    float acc[4][4] = {};
#pragma unroll 8
    for (int d = 0; d < D_IN; ++d) {
        float4 wv = *(const float4*)&Wt[d][tx * 4];
        float4 xv = *(const float4*)&xsT[d][ty * 4];
        acc[0][0] += xv.x * wv.x; acc[0][1] += xv.x * wv.y; acc[0][2] += xv.x * wv.z; acc[0][3] += xv.x * wv.w;
        acc[1][0] += xv.y * wv.x; acc[1][1] += xv.y * wv.y; acc[1][2] += xv.y * wv.z; acc[1][3] += xv.y * wv.w;
        acc[2][0] += xv.z * wv.x; acc[2][1] += xv.z * wv.y; acc[2][2] += xv.z * wv.z; acc[2][3] += xv.z * wv.w;
        acc[3][0] += xv.w * wv.x; acc[3][1] += xv.w * wv.y; acc[3][2] += xv.w * wv.z; acc[3][3] += xv.w * wv.w;
    }
#pragma unroll
    for (int i = 0; i < 4; ++i) {
        int rr = row0 + ty * 4 + i;
        if (rr < n) {
            float s = dk[rr];
            uint2 o;
            o.x = (unsigned)f2bf(acc[i][0] * s) | ((unsigned)f2bf(acc[i][1] * s) << 16);
            o.y = (unsigned)f2bf(acc[i][2] * s) | ((unsigned)f2bf(acc[i][3] * s) << 16);
            *(uint2*)&y2b[(size_t)rr * D_OUT + tx * 4] = o;
        }
    }
}

// ---------------------------------------------------------------------------
// SpMM: one wave per row; lane = (edge-slot grp = lane>>3, feat-oct fl =
// lane&7). Each step gathers 8 edges x 8 bf16 features per lane (uint4,
// 16B/lane; 8 lanes cover a 128B y2b row; one instruction = 8 full rows).
// Rows padded to multiple of 8 (dummy col n -> zero row). x2 unroll for MLP.
// Butterfly-reduce the 8 edge slots (xor 8,16,32) at the end.
// ---------------------------------------------------------------------------
__global__ __launch_bounds__(256) void k_spmm(
        const int* __restrict__ rowptr, const int* __restrict__ rowend,
        const int* __restrict__ colidx,
        const unsigned short* __restrict__ y2b, const float* __restrict__ dk,
        const float* __restrict__ bias, float* __restrict__ out, int n) {
    const int wv   = threadIdx.x >> 6;
    const int lane = threadIdx.x & 63;
    const int grp  = lane >> 3;    // edge slot 0..7
    const int fl   = lane & 7;     // feature octet: feats 8*fl .. 8*fl+7
    const int row  = blockIdx.x * 4 + wv;
    if (row >= n) return;

    const int start = rowptr[row];
    const int end   = rowend[row];    // start + padded count (mult of 8)

    float a0 = 0.f, a1 = 0.f, a2 = 0.f, a3 = 0.f;
    float a4 = 0.f, a5 = 0.f, a6 = 0.f, a7 = 0.f;
    int e = start;
    for (; e + 16 <= end; e += 16) {
        int c0 = colidx[e + grp];
        int c1 = colidx[e + 8 + grp];
        uint4 v0 = *(const uint4*)&y2b[(size_t)c0 * D_OUT + fl * 8];
        uint4 v1 = *(const uint4*)&y2b[(size_t)c1 * D_OUT + fl * 8];
        a0 += bflo(v0.x); a1 += bfhi(v0.x); a2 += bflo(v0.y); a3 += bfhi(v0.y);
        a4 += bflo(v0.z); a5 += bfhi(v0.z); a6 += bflo(v0.w); a7 += bfhi(v0.w);
        a0 += bflo(v1.x); a1 += bfhi(v1.x); a2 += bflo(v1.y); a3 += bfhi(v1.y);
        a4 += bflo(v1.z); a5 += bfhi(v1.z); a6 += bflo(v1.w); a7 += bfhi(v1.w);
    }
    if (e < end) {   // exactly 8 remain
        int c = colidx[e + grp];
        uint4 v = *(const uint4*)&y2b[(size_t)c * D_OUT + fl * 8];
        a0 += bflo(v.x); a1 += bfhi(v.x); a2 += bflo(v.y); a3 += bfhi(v.y);
        a4 += bflo(v.z); a5 += bfhi(v.z); a6 += bflo(v.w); a7 += bfhi(v.w);
    }

    // reduce the 8 edge slots (butterfly over lane bits 3,4,5)
    a0 += __shfl_xor(a0, 8);  a1 += __shfl_xor(a1, 8);
    a2 += __shfl_xor(a2, 8);  a3 += __shfl_xor(a3, 8);
    a4 += __shfl_xor(a4, 8);  a5 += __shfl_xor(a5, 8);
    a6 += __shfl_xor(a6, 8);  a7 += __shfl_xor(a7, 8);
    a0 += __shfl_xor(a0, 16); a1 += __shfl_xor(a1, 16);
    a2 += __shfl_xor(a2, 16); a3 += __shfl_xor(a3, 16);
    a4 += __shfl_xor(a4, 16); a5 += __shfl_xor(a5, 16);
    a6 += __shfl_xor(a6, 16); a7 += __shfl_xor(a7, 16);
    a0 += __shfl_xor(a0, 32); a1 += __shfl_xor(a1, 32);
    a2 += __shfl_xor(a2, 32); a3 += __shfl_xor(a3, 32);
    a4 += __shfl_xor(a4, 32); a5 += __shfl_xor(a5, 32);
    a6 += __shfl_xor(a6, 32); a7 += __shfl_xor(a7, 32);

    if (grp == 0) {
        uint4 sv = *(const uint4*)&y2b[(size_t)row * D_OUT + fl * 8];  // self loop
        a0 += bflo(sv.x); a1 += bfhi(sv.x); a2 += bflo(sv.y); a3 += bfhi(sv.y);
        a4 += bflo(sv.z); a5 += bfhi(sv.z); a6 += bflo(sv.w); a7 += bfhi(sv.w);
        float s = dk[row];
        float4 b0 = *(const float4*)&bias[fl * 8];
        float4 b1 = *(const float4*)&bias[fl * 8 + 4];
        float4 o0 = make_float4(s * a0 + b0.x, s * a1 + b0.y, s * a2 + b0.z, s * a3 + b0.w);
        float4 o1 = make_float4(s * a4 + b1.x, s * a5 + b1.y, s * a6 + b1.z, s * a7 + b1.w);
        float* op = &out[(size_t)row * D_OUT + fl * 8];
        *(float4*)op = o0;
        *(float4*)(op + 4) = o1;
    }
}

// ---------------------------------------------------------------------------
extern "C" void kernel_launch(void* const* d_in, const int* in_sizes, int n_in,
                              void* d_out, int out_size, void* d_ws, size_t ws_size,
                              hipStream_t stream) {
    const float* x    = (const float*)d_in[0];
    const void*  ei   = d_in[1];
    const float* W    = (const float*)d_in[2];
    const float* b    = (const float*)d_in[3];
    const int*   kptr = (const int*)d_in[4];

    const int       n = in_sizes[0] / D_IN;            // 100000
    const long long E = (long long)in_sizes[1] / 2;    // 3200000
    const int      nb = (n + SBROWS - 1) / SBROWS;     // 521 (<= NBPAD, <= 768)

    char* ws = (char*)d_ws;
    size_t off = 0;
    auto alloc = [&](size_t bytes) -> void* {
        void* p = ws + off;
        off += (bytes + 255) & ~(size_t)255;
        return p;
    };
    int*          flag   = (int*)alloc(4);
    int*          gcur   = (int*)alloc((size_t)8 * NBPAD * 4);   // per-rep contiguous
    int*          sbbase = (int*)alloc((size_t)NBPAD * 4);
    int*          rowptr = (int*)alloc((size_t)n * 4);
    int*          rowend = (int*)alloc((size_t)n * 4);
    float*        dk     = (float*)alloc((size_t)n * 4);
    // colidx: E + worst-case pad (nb * 7*SBROWS) ints = 15.6 MB
    int*          colidx = (int*)alloc(((size_t)E + (size_t)nb * 7 * SBROWS) * 4);
    // parts (nb*8*CAPR*4 = 17.1 MB); y2b (bf16, n+1 rows = 12.8 MB) aliases it
    size_t p_bytes  = (size_t)nb * 8 * CAPR * 4;
    size_t y2_bytes = ((size_t)n + 1) * D_OUT * 2;
    unsigned int*   parts = (unsigned int*)alloc(p_bytes > y2_bytes ? p_bytes : y2_bytes);
    unsigned short* y2b   = (unsigned short*)parts;
    (void)ws_size; (void)n_in; (void)out_size;

    hipMemsetAsync(gcur, 0, (size_t)8 * NBPAD * 4, stream);
    k_detect<<<1, 256, 0, stream>>>((const unsigned int*)ei, flag);
    k_split3<<<1024, 256, 0, stream>>>(ei, flag, gcur, parts, E, nb);
    k_scan_sb<<<1, 256, 0, stream>>>(gcur, sbbase, nb);
    k_cidx<<<nb, 256, 0, stream>>>(parts, gcur, sbbase, rowptr, rowend,
                                   dk, kptr, colidx, nb, n);
    // zero row n of y2b (gather target for pad columns)
    hipMemsetAsync(y2b + (size_t)n * D_OUT, 0, D_OUT * 2, stream);
    k_gemm<<<(n + 63) / 64, 256, 0, stream>>>(x, W, dk, y2b, n);
    k_spmm<<<(n + 3) / 4, 256, 0, stream>>>(rowptr, rowend, colidx, y2b, dk, b,
                                            (float*)d_out, n);
}

// Round 11
// 151.239 us; speedup vs baseline: 3.0850x; 1.0145x over previous
//
#include <hip/hip_runtime.h>
#include <hip/hip_bf16.h>
#include <math.h>

#define D_IN   128
#define D_OUT  64
#define SHIFT  8            // local-row bits in packed pair (SBROWS <= 256)
#define PMASK  ((1u << SHIFT) - 1u)
#define SBROWS 192          // rows per bucket
#define NBPAD  528          // padded bucket count (>= nb=521)
#define CAPR   1024         // capacity per (bucket, xcd-replica)
#define CLDS_N 9536         // bucket edges (<=8192) + worst-case pad (1344)
#define SPLIT_TILE 4096

__device__ __forceinline__ unsigned short f2bf(float f) {   // RTNE f32 -> bf16
    unsigned u = __float_as_uint(f);
    return (unsigned short)((u + 0x7FFFu + ((u >> 16) & 1u)) >> 16);
}
__device__ __forceinline__ float bflo(unsigned v) { return __uint_as_float(v << 16); }
__device__ __forceinline__ float bfhi(unsigned v) { return __uint_as_float(v & 0xFFFF0000u); }

// ---------------------------------------------------------------------------
// Edge-index dtype detection (int64 vs int32, little-endian high-word probe).
// ---------------------------------------------------------------------------
__global__ void k_detect(const unsigned int* __restrict__ u, int* __restrict__ flag) {
    __shared__ int nonzero;
    if (threadIdx.x == 0) nonzero = 0;
    __syncthreads();
    if (u[2 * threadIdx.x + 1] != 0u) atomicOr(&nonzero, 1);
    __syncthreads();
    if (threadIdx.x == 0) *flag = (nonzero == 0) ? 1 : 0;  // 1 => int64
}

__device__ __forceinline__ int edge_val(const void* ei, int is64, long long idx) {
    return is64 ? (int)((const long long*)ei)[idx] : ((const int*)ei)[idx];
}

// ---------------------------------------------------------------------------
// Fused kernel: SPLIT blocks (edge multisplit -> 521 buckets x 8 XCD-replica
// segments) and GEMM blocks (y2b[r] = bf16(x[r] @ W^T), 64-row tiles),
// interleaved 1:2 via bid%3. GEMM takes dkg: nullptr in fused mode (store
// raw p; k_cidx rescales rows by dk later -- dk[c] is NOT known here), or
// the dk array in fallback mode (runs after k_cidx; scale like R9).
// mode 0 = split only, 1 = gemm only, 2 = interleaved.
// ---------------------------------------------------------------------------
__global__ __launch_bounds__(256) void k_fused(
        const void* __restrict__ ei, const int* __restrict__ flag,
        int* __restrict__ gcur, unsigned int* __restrict__ parts,
        long long E, int nb,
        const float* __restrict__ x, const float* __restrict__ W,
        const float* __restrict__ dkg,
        unsigned short* __restrict__ y2b, int n,
        int nsplit, int ngemm, int mode) {
    __shared__ __align__(16) char smem[65536];
    const int tid = threadIdx.x;
    const int bid = blockIdx.x;

    int is_split, widx;
    if (mode == 2) {
        is_split = ((bid % 3) == 0);
        widx = is_split ? (bid / 3) : (bid - bid / 3 - 1);
    } else {
        is_split = (mode == 0);
        widx = bid;
    }

    if (is_split) {
        if (widx >= nsplit) return;
        int* scnt  = (int*)smem;
        int* sbase = (int*)(smem + 544 * 4);
        const int is64 = *flag;
        const int rep  = bid & 7;
        const long long t0 = (long long)widx * SPLIT_TILE;

        for (int i = tid; i < nb; i += 256) scnt[i] = 0;
        __syncthreads();
        int sb16[16], rk16[16];
        unsigned int q16[16];
#pragma unroll
        for (int j = 0; j < 16; ++j) {
            long long e = t0 + (long long)j * 256 + tid;
            if (e < E) {
                int r = edge_val(ei, is64, e);
                int c = edge_val(ei, is64, E + e);
                unsigned sb = (unsigned)r / SBROWS;   // const divisor -> magic mul
                sb16[j] = (int)sb;
                q16[j]  = ((unsigned int)c << SHIFT) | (unsigned int)(r - sb * SBROWS);
                rk16[j] = atomicAdd(&scnt[sb], 1);
            } else sb16[j] = -1;
        }
        __syncthreads();
        for (int i = tid; i < nb; i += 256)
            if (scnt[i] > 0) sbase[i] = atomicAdd(&gcur[rep * NBPAD + i], scnt[i]);
        __syncthreads();
#pragma unroll
        for (int j = 0; j < 16; ++j) {
            if (sb16[j] >= 0) {
                int pos = sbase[sb16[j]] + rk16[j];
                if (pos < CAPR)
                    parts[((size_t)sb16[j] * 8 + rep) * CAPR + pos] = q16[j];
            }
        }
    } else {
        if (widx >= ngemm) return;
        float (*Wt)[D_OUT] = (float(*)[D_OUT])smem;          // 32 KB
        float (*xsT)[64]   = (float(*)[64])(smem + 32768);   // 32 KB
        const int row0 = widx * 64;

        {
            const int c = tid & 63;
            const int dblk = (tid >> 6) * 32;
            const float* wr = &W[c * D_IN + dblk];
#pragma unroll
            for (int j = 0; j < 32; j += 4) {
                float4 w4 = *(const float4*)(wr + j);
                Wt[dblk + j + 0][c] = w4.x;
                Wt[dblk + j + 1][c] = w4.y;
                Wt[dblk + j + 2][c] = w4.z;
                Wt[dblk + j + 3][c] = w4.w;
            }
        }
        {
            const int r = tid & 63;
            const int h = tid >> 6;
            const int grow = row0 + r;
            const float* xr = &x[(size_t)grow * D_IN + h * 32];
#pragma unroll
            for (int j = 0; j < 32; j += 4) {
                float4 v = (grow < n) ? *(const float4*)(xr + j)
                                      : make_float4(0.f, 0.f, 0.f, 0.f);
                xsT[h * 32 + j + 0][r] = v.x;
                xsT[h * 32 + j + 1][r] = v.y;
                xsT[h * 32 + j + 2][r] = v.z;
                xsT[h * 32 + j + 3][r] = v.w;
            }
        }
        __syncthreads();

        const int tx = tid & 15;
        const int ty = tid >> 4;
        float acc[4][4] = {};
#pragma unroll 8
        for (int d = 0; d < D_IN; ++d) {
            float4 wv = *(const float4*)&Wt[d][tx * 4];
            float4 xv = *(const float4*)&xsT[d][ty * 4];
            acc[0][0] += xv.x * wv.x; acc[0][1] += xv.x * wv.y; acc[0][2] += xv.x * wv.z; acc[0][3] += xv.x * wv.w;
            acc[1][0] += xv.y * wv.x; acc[1][1] += xv.y * wv.y; acc[1][2] += xv.y * wv.z; acc[1][3] += xv.y * wv.w;
            acc[2][0] += xv.z * wv.x; acc[2][1] += xv.z * wv.y; acc[2][2] += xv.z * wv.z; acc[2][3] += xv.z * wv.w;
            acc[3][0] += xv.w * wv.x; acc[3][1] += xv.w * wv.y; acc[3][2] += xv.w * wv.z; acc[3][3] += xv.w * wv.w;
        }
#pragma unroll
        for (int i = 0; i < 4; ++i) {
            int rr = row0 + ty * 4 + i;
            if (rr < n) {
                float s = (dkg != nullptr) ? dkg[rr] : 1.0f;
                uint2 o;
                o.x = (unsigned)f2bf(acc[i][0] * s) | ((unsigned)f2bf(acc[i][1] * s) << 16);
                o.y = (unsigned)f2bf(acc[i][2] * s) | ((unsigned)f2bf(acc[i][3] * s) << 16);
                *(uint2*)&y2b[(size_t)rr * D_OUT + tx * 4] = o;
            }
        }
    }
}

// ---------------------------------------------------------------------------
// Scan bucket sizes (sum of 8 replicas) -> colidx base per bucket.
// Capacity spacing = size + 7*SBROWS (worst-case pad-to-8 per row).
// ---------------------------------------------------------------------------
__global__ void k_scan_sb(const int* __restrict__ gcur, int* __restrict__ sbbase,
                          int nb) {
    __shared__ int sm[256];
    const int tid = threadIdx.x;
    int v[3]; int t = 0;
#pragma unroll
    for (int j = 0; j < 3; ++j) {
        int idx = tid * 3 + j;
        int s = 0;
        if (idx < nb) {
#pragma unroll
            for (int rep = 0; rep < 8; ++rep)
                s += min(gcur[rep * NBPAD + idx], CAPR);
            s += 7 * SBROWS;
        }
        v[j] = s; t += s;
    }
    sm[tid] = t; __syncthreads();
    for (int o = 1; o < 256; o <<= 1) {
        int a = (tid >= o) ? sm[tid - o] : 0;
        __syncthreads();
        sm[tid] += a;
        __syncthreads();
    }
    int run = sm[tid] - t;
#pragma unroll
    for (int j = 0; j < 3; ++j) {
        int idx = tid * 3 + j;
        if (idx < nb) { sbbase[idx] = run; run += v[j]; }
    }
}

// ---------------------------------------------------------------------------
// CSR-ify one bucket in LDS from its 8 replica segments. Rows padded to a
// multiple of 8 (dummy col n -> zero row in y2b). Emits rowptr, rowend,
// dk = (deg+1)^(-k/2), sequential colidx (plain columns). If y2bs != null
// (fused mode), also rescales this bucket's y2b rows in place by dk[row]
// (the block owns rows [row0,row0+rows_here) and just computed their dk).
// ---------------------------------------------------------------------------
__global__ __launch_bounds__(256) void k_cidx(const unsigned int* __restrict__ parts,
        const int* __restrict__ gcur, const int* __restrict__ sbbase,
        int* __restrict__ rowptr, int* __restrict__ rowend,
        float* __restrict__ dk, const int* __restrict__ kptr,
        unsigned int* __restrict__ colidx,
        unsigned short* __restrict__ y2bs,
        int nb, int n) {
    __shared__ int scnt[256];
    __shared__ int ssum[256];
    __shared__ int scur[256];
    __shared__ float sdkf[256];
    __shared__ unsigned int clds[CLDS_N];   // 37.3 KB

    const int b = blockIdx.x;
    if (b >= nb) return;
    const int row0 = b * SBROWS;
    if (row0 >= n) return;
    const int rows_here = min(SBROWS, n - row0);
    const int tid = threadIdx.x;
    const int sbb = sbbase[b];

    int szs[8];
#pragma unroll
    for (int rep = 0; rep < 8; ++rep) szs[rep] = min(gcur[rep * NBPAD + b], CAPR);

    scnt[tid] = 0;
    __syncthreads();

    unsigned int q[32]; int rl[32];
#pragma unroll
    for (int rep = 0; rep < 8; ++rep) {
        const unsigned int* p = parts + ((size_t)b * 8 + rep) * CAPR;
#pragma unroll
        for (int j = 0; j < 4; ++j) {
            const int idx = rep * 4 + j;
            const int i = j * 256 + tid;
            if (i < szs[rep]) {
                q[idx]  = p[i];
                rl[idx] = (int)(q[idx] & PMASK);
                atomicAdd(&scnt[rl[idx]], 1);
            } else rl[idx] = -1;
        }
    }
    __syncthreads();

    // padded counts (multiple of 8), inclusive scan
    int truec = scnt[tid];
    int padc  = (tid < rows_here) ? ((truec + 7) & ~7) : 0;
    ssum[tid] = padc;
    __syncthreads();
    for (int o = 1; o < 256; o <<= 1) {
        int a = (tid >= o) ? ssum[tid - o] : 0;
        __syncthreads();
        ssum[tid] += a;
        __syncthreads();
    }
    int excl = ssum[tid] - padc;
    scur[tid] = excl;
    if (tid < rows_here) {
        rowptr[row0 + tid] = sbb + excl;
        rowend[row0 + tid] = sbb + ssum[tid];   // start + padded count (mult 8)
        int kk = kptr[0];
        if (kk < 0 || kk > 1000) {
            float kf = ((const float*)kptr)[0];
            kk = (kf > 0.f && kf < 1000.f) ? (int)(kf + 0.5f) : 2;
        }
        float deg  = (float)(truec + 1);
        float dinv = 1.0f / sqrtf(deg);
        float v = 1.0f;
        for (int t = 0; t < kk; ++t) v *= dinv;
        dk[row0 + tid] = v;
        sdkf[tid] = v;
        for (int j = truec; j < padc; ++j) {    // pad -> dummy col n (zero row)
            int pos = excl + j;
            if (pos < CLDS_N) clds[pos] = (unsigned int)n;
        }
    }
    __syncthreads();

#pragma unroll
    for (int rep = 0; rep < 8; ++rep) {
#pragma unroll
        for (int j = 0; j < 4; ++j) {
            const int idx = rep * 4 + j;
            if (rl[idx] >= 0) {
                int pos = atomicAdd(&scur[rl[idx]], 1);
                if (pos < CLDS_N) clds[pos] = q[idx] >> SHIFT;
            }
        }
    }
    __syncthreads();

    const int ptotal = min(ssum[255], CLDS_N);
    for (int i = tid; i < ptotal; i += 256)     // sequential write-out
        colidx[sbb + i] = clds[i];

    // fused mode: rescale this bucket's y2b rows by dk[row] (in place, bf16)
    if (y2bs != nullptr) {
        for (int w = tid; w < rows_here * 16; w += 256) {
            const int r  = w >> 4;       // local row
            const int qd = w & 15;       // quad of 4 bf16
            const float s = sdkf[r];
            unsigned short* yp = &y2bs[(size_t)(row0 + r) * D_OUT + qd * 4];
            uint2 v = *(uint2*)yp;
            uint2 o;
            o.x = (unsigned)f2bf(s * bflo(v.x)) | ((unsigned)f2bf(s * bfhi(v.x)) << 16);
            o.y = (unsigned)f2bf(s * bflo(v.y)) | ((unsigned)f2bf(s * bfhi(v.y)) << 16);
            *(uint2*)yp = o;
        }
    }
}

// ---------------------------------------------------------------------------
// SpMM (verified R9 form): one wave per row; lane = (edge-slot grp = lane>>3,
// feat-oct fl = lane&7). Per step: 8 edges x 8 bf16 features per lane (uint4,
// 16B/lane; 8 lanes cover a 128B y2b row). y2b rows pre-scaled by dk[col].
// Rows padded to multiple of 8 (dummy col n -> zero row). Butterfly-reduce
// slots (xor 8,16,32). out[r] = dk[r]*(sum + y2b[r]) + bias.
// ---------------------------------------------------------------------------
__global__ __launch_bounds__(256) void k_spmm(
        const int* __restrict__ rowptr, const int* __restrict__ rowend,
        const unsigned int* __restrict__ colidx,
        const unsigned short* __restrict__ y2b, const float* __restrict__ dk,
        const float* __restrict__ bias, float* __restrict__ out, int n) {
    const int wv   = threadIdx.x >> 6;
    const int lane = threadIdx.x & 63;
    const int grp  = lane >> 3;    // edge slot 0..7
    const int fl   = lane & 7;     // feature octet
    const int row  = blockIdx.x * 4 + wv;
    if (row >= n) return;

    const int start = rowptr[row];
    const int end   = rowend[row];    // start + padded count (mult of 8)

    float a0 = 0.f, a1 = 0.f, a2 = 0.f, a3 = 0.f;
    float a4 = 0.f, a5 = 0.f, a6 = 0.f, a7 = 0.f;
    int e = start;
    for (; e + 16 <= end; e += 16) {
        unsigned int c0 = colidx[e + grp];
        unsigned int c1 = colidx[e + 8 + grp];
        uint4 v0 = *(const uint4*)&y2b[(size_t)c0 * D_OUT + fl * 8];
        uint4 v1 = *(const uint4*)&y2b[(size_t)c1 * D_OUT + fl * 8];
        a0 += bflo(v0.x); a1 += bfhi(v0.x); a2 += bflo(v0.y); a3 += bfhi(v0.y);
        a4 += bflo(v0.z); a5 += bfhi(v0.z); a6 += bflo(v0.w); a7 += bfhi(v0.w);
        a0 += bflo(v1.x); a1 += bfhi(v1.x); a2 += bflo(v1.y); a3 += bfhi(v1.y);
        a4 += bflo(v1.z); a5 += bfhi(v1.z); a6 += bflo(v1.w); a7 += bfhi(v1.w);
    }
    if (e < end) {   // exactly 8 remain
        unsigned int c = colidx[e + grp];
        uint4 v = *(const uint4*)&y2b[(size_t)c * D_OUT + fl * 8];
        a0 += bflo(v.x); a1 += bfhi(v.x); a2 += bflo(v.y); a3 += bfhi(v.y);
        a4 += bflo(v.z); a5 += bfhi(v.z); a6 += bflo(v.w); a7 += bfhi(v.w);
    }

    // reduce the 8 edge slots (butterfly over lane bits 3,4,5)
    a0 += __shfl_xor(a0, 8);  a1 += __shfl_xor(a1, 8);
    a2 += __shfl_xor(a2, 8);  a3 += __shfl_xor(a3, 8);
    a4 += __shfl_xor(a4, 8);  a5 += __shfl_xor(a5, 8);
    a6 += __shfl_xor(a6, 8);  a7 += __shfl_xor(a7, 8);
    a0 += __shfl_xor(a0, 16); a1 += __shfl_xor(a1, 16);
    a2 += __shfl_xor(a2, 16); a3 += __shfl_xor(a3, 16);
    a4 += __shfl_xor(a4, 16); a5 += __shfl_xor(a5, 16);
    a6 += __shfl_xor(a6, 16); a7 += __shfl_xor(a7, 16);
    a0 += __shfl_xor(a0, 32); a1 += __shfl_xor(a1, 32);
    a2 += __shfl_xor(a2, 32); a3 += __shfl_xor(a3, 32);
    a4 += __shfl_xor(a4, 32); a5 += __shfl_xor(a5, 32);
    a6 += __shfl_xor(a6, 32); a7 += __shfl_xor(a7, 32);

    if (grp == 0) {
        uint4 sv = *(const uint4*)&y2b[(size_t)row * D_OUT + fl * 8];  // self loop
        a0 += bflo(sv.x); a1 += bfhi(sv.x); a2 += bflo(sv.y); a3 += bfhi(sv.y);
        a4 += bflo(sv.z); a5 += bfhi(sv.z); a6 += bflo(sv.w); a7 += bfhi(sv.w);
        float s = dk[row];
        float4 b0 = *(const float4*)&bias[fl * 8];
        float4 b1 = *(const float4*)&bias[fl * 8 + 4];
        float4 o0 = make_float4(s * a0 + b0.x, s * a1 + b0.y, s * a2 + b0.z, s * a3 + b0.w);
        float4 o1 = make_float4(s * a4 + b1.x, s * a5 + b1.y, s * a6 + b1.z, s * a7 + b1.w);
        float* op = &out[(size_t)row * D_OUT + fl * 8];
        *(float4*)op = o0;
        *(float4*)(op + 4) = o1;
    }
}

// ---------------------------------------------------------------------------
extern "C" void kernel_launch(void* const* d_in, const int* in_sizes, int n_in,
                              void* d_out, int out_size, void* d_ws, size_t ws_size,
                              hipStream_t stream) {
    const float* x    = (const float*)d_in[0];
    const void*  ei   = d_in[1];
    const float* W    = (const float*)d_in[2];
    const float* b    = (const float*)d_in[3];
    const int*   kptr = (const int*)d_in[4];

    const int       n = in_sizes[0] / D_IN;            // 100000
    const long long E = (long long)in_sizes[1] / 2;    // 3200000
    const int      nb = (n + SBROWS - 1) / SBROWS;     // 521
    const int  nsplit = (int)((E + SPLIT_TILE - 1) / SPLIT_TILE);  // 782
    const int   ngemm = (n + 63) / 64;                 // 1563

    char* ws = (char*)d_ws;
    size_t off = 0;
    auto alloc = [&](size_t bytes) -> void* {
        void* p = ws + off;
        off += (bytes + 255) & ~(size_t)255;
        return p;
    };
    int*          flag   = (int*)alloc(4);
    int*          gcur   = (int*)alloc((size_t)8 * NBPAD * 4);
    int*          sbbase = (int*)alloc((size_t)NBPAD * 4);
    int*          rowptr = (int*)alloc((size_t)n * 4);
    int*          rowend = (int*)alloc((size_t)n * 4);
    float*        dk     = (float*)alloc((size_t)n * 4);
    unsigned int* colidx = (unsigned int*)alloc(((size_t)E + (size_t)nb * 7 * SBROWS) * 4);

    const size_t parts_b = (size_t)nb * 8 * CAPR * 4;          // 17.07 MB
    const size_t y2b_b   = ((size_t)n + 1) * D_OUT * 2;        // 12.8 MB
    // fused mode needs parts and y2b live simultaneously (separate buffers)
    const size_t need_fused = off + ((parts_b + 255) & ~(size_t)255)
                                  + ((y2b_b + 255) & ~(size_t)255);
    const bool fused_ok = (ws_size >= need_fused);

    unsigned int*   parts;
    unsigned short* y2b;
    if (fused_ok) {
        parts = (unsigned int*)alloc(parts_b);
        y2b   = (unsigned short*)alloc(y2b_b);
    } else {
        parts = (unsigned int*)alloc(parts_b > y2b_b ? parts_b : y2b_b);
        y2b   = (unsigned short*)parts;   // R9-style alias: gemm runs after cidx
    }
    (void)n_in; (void)out_size;

    hipMemsetAsync(gcur, 0, (size_t)8 * NBPAD * 4, stream);
    k_detect<<<1, 256, 0, stream>>>((const unsigned int*)ei, flag);

    if (fused_ok) {
        hipMemsetAsync(y2b + (size_t)n * D_OUT, 0, D_OUT * 2, stream);
        const int grid = 3 * nsplit;   // split slots = nsplit, gemm slots cover ngemm
        k_fused<<<grid, 256, 0, stream>>>(ei, flag, gcur, parts, E, nb,
                                          x, W, nullptr, y2b, n, nsplit, ngemm, 2);
        k_scan_sb<<<1, 256, 0, stream>>>(gcur, sbbase, nb);
        k_cidx<<<nb, 256, 0, stream>>>(parts, gcur, sbbase, rowptr, rowend,
                                       dk, kptr, colidx, y2b, nb, n);
    } else {
        k_fused<<<nsplit, 256, 0, stream>>>(ei, flag, gcur, parts, E, nb,
                                            x, W, nullptr, y2b, n, nsplit, ngemm, 0);
        k_scan_sb<<<1, 256, 0, stream>>>(gcur, sbbase, nb);
        k_cidx<<<nb, 256, 0, stream>>>(parts, gcur, sbbase, rowptr, rowend,
                                       dk, kptr, colidx, nullptr, nb, n);
        hipMemsetAsync(y2b + (size_t)n * D_OUT, 0, D_OUT * 2, stream);
        k_fused<<<ngemm, 256, 0, stream>>>(ei, flag, gcur, parts, E, nb,
                                           x, W, dk, y2b, n, nsplit, ngemm, 1);
    }
    k_spmm<<<(n + 3) / 4, 256, 0, stream>>>(rowptr, rowend, colidx, y2b, dk, b,
                                            (float*)d_out, n);
}